// Round 7
// baseline (114.312 us; speedup 1.0000x reference)
//
#include <hip/hip_runtime.h>
#include <cstdint>
#include <cstddef>

#define NQ 900
#define NC 91
#define NFLAT (NQ * NC)        // 81900
#define NF4 (NFLAT / 4)        // 20475
#define BS 8
#define PRE_TOPK 10000
#define TOPK 100
#define IOU_THR 0.7f
#define NSL 8                  // slices per batch in K1
#define K1T 256
#define NT 1024
#define NWAVES (NT / 64)
#define HB 2048                // bins on z over [-4,4)
#define BINGUESS 1280          // bin_of(1.0): pool = z >= 1.0 (~13K of 81.9K)
#define SLICECAP 2048          // per (batch,slice) pool cap (exp 1628 +10s)
#define POOLCAP 15360          // K2 LDS pool cap (exp 13000 +22s)
#define TCAP 1088              // sorted-top capacity
#define E2CAND 1024            // target sorted-prefix length
#define BBCAP 512              // crossing-bin capacity (exp ~64)
#define ELIG 0x40000000
#define LENMASK 0x3FFFFFFF

// ws layout (bytes); every region fully overwritten by K1 each launch (poison-safe)
#define HIST_OFF 0                                   // u32 [BS][NSL][HB]  = 512 KB
#define CNT_OFF  (BS * NSL * HB * 4)                 // u32 [BS][NSL]      = 256 B
#define POOL_OFF (CNT_OFF + BS * NSL * 4)            // u64 [BS][NSL][SLICECAP] = 1 MB
#define WS_REQ   ((size_t)POOL_OFF + (size_t)BS * NSL * SLICECAP * 8)

// sigmoid monotone => order on raw logit z == order on prob.
__device__ __forceinline__ unsigned int mono_u(float z) {
    unsigned int b = __float_as_uint(z);
    return b ^ ((unsigned int)((int)b >> 31) | 0x80000000u);
}
__device__ __forceinline__ float inv_mono(unsigned int u) {
    unsigned int b = (u & 0x80000000u) ? (u ^ 0x80000000u) : ~u;
    return __uint_as_float(b);
}
// 49-bit distinct key == lax.top_k order (score desc, idx asc)
__device__ __forceinline__ unsigned long long make_key(unsigned int u, int i) {
    return ((unsigned long long)u << 17) | (unsigned long long)(131071 - i);
}
__device__ __forceinline__ int bin_of(float z) {
    float t = (z + 4.0f) * 256.0f;
    t = fmaxf(t, 0.0f); t = fminf(t, 2047.0f);
    return (int)t;
}
__device__ __forceinline__ int bin_of_key(unsigned long long k) {
    return bin_of(inv_mono((unsigned int)(k >> 17)));
}

// ---------------- K1: per-slice histogram + candidate pool ----------------
extern "C" __global__ __launch_bounds__(K1T)
void k1_hist_pool(const float* __restrict__ logits, void* __restrict__ ws) {
    __shared__ int h[HB];
    __shared__ unsigned long long pool[SLICECAP];
    __shared__ int pc;
    const int sl = blockIdx.x, b = blockIdx.y;
    const int tid = threadIdx.x, lane = tid & 63;
    const unsigned long long laneLT = (1ULL << lane) - 1ULL;
    const float* lg = logits + (size_t)b * NFLAT;
    for (int i = tid; i < HB; i += K1T) h[i] = 0;
    if (tid == 0) pc = 0;
    __syncthreads();
    const int j0 = (sl * NF4) / NSL, j1 = ((sl + 1) * NF4) / NSL;
    for (int j = j0 + tid; j < j1; j += K1T) {
        const float4 v = ((const float4*)lg)[j];
        const float zv[4] = { v.x, v.y, v.z, v.w };
        #pragma unroll
        for (int q = 0; q < 4; ++q) {
            const int bk = bin_of(zv[q]);
            atomicAdd(&h[bk], 1);
            const bool cand = bk >= BINGUESS;
            const unsigned long long mask = __ballot(cand);
            const int n = __popcll(mask);
            int base = 0;
            if (lane == 0 && n) base = atomicAdd(&pc, n);
            base = __shfl(base, 0, 64);
            if (cand) {
                const int p2 = base + __popcll(mask & laneLT);
                if (p2 < SLICECAP) pool[p2] = make_key(mono_u(zv[q]), 4 * j + q);
            }
        }
    }
    __syncthreads();
    unsigned int* hw = (unsigned int*)((char*)ws + HIST_OFF) + ((size_t)b * NSL + sl) * HB;
    for (int i = tid; i < HB; i += K1T) hw[i] = (unsigned int)h[i];
    unsigned int* cw = (unsigned int*)((char*)ws + CNT_OFF);
    if (tid == 0) cw[b * NSL + sl] = (unsigned int)pc;   // raw; K2 checks overflow
    unsigned long long* pw = (unsigned long long*)((char*)ws + POOL_OFF)
                             + ((size_t)b * NSL + sl) * SLICECAP;
    const int c = pc < SLICECAP ? pc : SLICECAP;
    for (int i = tid; i < c; i += K1T) pw[i] = pool[i];
}

// ---------------- K2: per-batch selection + sorted-scan NMS ----------------
extern "C" __global__ __launch_bounds__(NT)
void k2_select_nms(const float* __restrict__ logits,
                   const float* __restrict__ pboxes,
                   const float* __restrict__ tsizes,
                   float* __restrict__ out,
                   const void* __restrict__ ws,
                   const int forceBad) {
    __shared__ unsigned long long sPool[POOLCAP]; // 120 KB
    __shared__ unsigned long long sTop[TCAP];     // 8.5 KB
    __shared__ unsigned long long sBinB[BBCAP];   // 4 KB
    __shared__ int sHist[HB];                     // counts (+ELIG bit later)
    __shared__ int sScan[HB];                     // exclusive-above; scatter cursors
    __shared__ unsigned long long sLazy[64];
    __shared__ float sKx1[TOPK], sKy1[TOPK], sKx2[TOPK], sKy2[TOPK], sKa[TOPK];
    __shared__ float sFirst[6];
    __shared__ float sRedF[NWAVES];
    __shared__ int sWTot[NWAVES], sWSuf[NWAVES];
    __shared__ int sFlag, sB, sRem, sAbove, sKept, sBinBCnt, sPos, sE2, sLin, sCnt;
    __shared__ unsigned long long sT;
    __shared__ float sBmax;

    const int b = blockIdx.x;
    const int tid = threadIdx.x;
    const int wid = tid >> 6, lane = tid & 63;
    const float* lg = logits + (size_t)b * NFLAT;
    const float* bx = pboxes + (size_t)b * NQ * 4;
    const float img_h = tsizes[b * 2 + 0], img_w = tsizes[b * 2 + 1];
    const unsigned long long laneLT = (1ULL << lane) - 1ULL;

    if (tid == 0) { sFlag = forceBad; sBinBCnt = 0; sPos = 0; sLin = 0; sCnt = 0;
                    sB = BINGUESS; sAbove = 0; sRem = 1; }
    __syncthreads();

    // ---- sum the 8 partial histograms ----
    if (!forceBad) {
        const unsigned int* hw = (const unsigned int*)((const char*)ws + HIST_OFF)
                                 + (size_t)b * NSL * HB;
        for (int i = tid; i < HB; i += NT) {
            int s = 0;
            #pragma unroll
            for (int sl = 0; sl < NSL; ++sl) s += (int)hw[(size_t)sl * HB + i];
            sHist[i] = s;
        }
    } else {
        for (int i = tid; i < HB; i += NT) sHist[i] = 0;
    }
    __syncthreads();

    // ---- shfl-based hierarchical suffix scan over 2048 bins ----
    {
        const int b0 = 2 * tid, b1 = 2 * tid + 1;
        const int h0 = sHist[b0], h1 = sHist[b1];
        const int s = h0 + h1;
        int v = s;
        #pragma unroll
        for (int off = 1; off < 64; off <<= 1) {
            const int o = __shfl(v, lane + off, 64);
            if (lane + off < 64) v += o;
        }
        if (lane == 0) sWTot[wid] = v;
        __syncthreads();
        if (wid == 0) {
            int t = (lane < NWAVES) ? sWTot[lane] : 0;
            #pragma unroll
            for (int off = 1; off < NWAVES; off <<= 1) {
                const int o = __shfl(t, lane + off, 64);
                if (lane + off < NWAVES) t += o;
            }
            if (lane < NWAVES) sWSuf[lane] = t;
        }
        __syncthreads();
        const int afterWave = sWSuf[wid] - sWTot[wid];
        const int afterPairs = (v - s) + afterWave;
        const int si1 = h1 + afterPairs;
        const int si0 = h0 + si1;
        sScan[b0] = si1;
        sScan[b1] = afterPairs;
        if (si0 >= PRE_TOPK && si1 < PRE_TOPK)        { sB = b0; sAbove = si1;        sRem = PRE_TOPK - si1; }
        if (si1 >= PRE_TOPK && afterPairs < PRE_TOPK) { sB = b1; sAbove = afterPairs; sRem = PRE_TOPK - afterPairs; }
    }
    __syncthreads();
    if (tid == 0 && sB < BINGUESS) sFlag = 1;   // pool doesn't cover top-10000
    __syncthreads();

    // ---- load candidate pool segments -> contiguous LDS ----
    if (!forceBad && !sFlag) {
        const unsigned int* cw = (const unsigned int*)((const char*)ws + CNT_OFF) + b * NSL;
        const unsigned long long* pw = (const unsigned long long*)((const char*)ws + POOL_OFF)
                                       + (size_t)b * NSL * SLICECAP;
        int off = 0, bad2 = 0;
        for (int sl = 0; sl < NSL; ++sl) {
            const int c = (int)cw[sl];
            if (c > SLICECAP || off + c > POOLCAP) { bad2 = 1; break; }
            for (int i = tid; i < c; i += NT) sPool[off + i] = pw[(size_t)sl * SLICECAP + i];
            off += c;
        }
        if (tid == 0) { if (bad2) sFlag = 1; sCnt = off; }
    }
    __syncthreads();
    int bad = sFlag;
    const int cnt = sCnt;
    const int B = sB, above = sAbove, rem = sRem;

    if (!bad) {
        // ---- collect crossing bin from flat pool (ballot append) ----
        const int lim = (cnt + NT - 1) / NT * NT;
        for (int off = tid; off < lim; off += NT) {
            const bool have = off < cnt;
            const unsigned long long k = have ? sPool[off] : 0ULL;
            const bool isB = have && (bin_of_key(k) == B);
            const unsigned long long mask = __ballot(isB);
            const int n = __popcll(mask);
            int base = 0;
            if (lane == 0 && n) base = atomicAdd(&sBinBCnt, n);
            base = __shfl(base, 0, 64);
            if (isB) {
                const int p2 = base + __popcll(mask & laneLT);
                if (p2 < BBCAP) sBinB[p2] = k;
            }
        }
        __syncthreads();
        if (tid == 0 && sBinBCnt > BBCAP) sFlag = 1;
        __syncthreads();
        bad = sFlag;
    }

    if (!bad) {
        // ---- exact sort of crossing bin; T = 10000th key ----
        const int cntB = sBinBCnt;
        unsigned long long kk = 0ULL; int r = -1;
        if (tid < cntB) {
            kk = sBinB[tid]; r = 0;
            for (int q = 0; q < cntB; ++q) r += (sBinB[q] > kk) ? 1 : 0;
        }
        __syncthreads();
        if (r >= 0) sBinB[r] = kk;
        __syncthreads();
        if (tid == 0) sT = sBinB[rem - 1];
        __syncthreads();
        const unsigned long long T = sT;

        // ---- bmax over exact top-10000 (pool membership: key >= T) ----
        float lmax = -3.4e38f;
        for (int p = tid; p < cnt; p += NT) {
            const unsigned long long k = sPool[p];
            if (k >= T) {
                const int i = 131071 - (int)(k & 0x1FFFFULL);
                const int bi = i / NC;
                const float4 bb = ((const float4*)bx)[bi];
                const float x1 = (bb.x - 0.5f * bb.z) * img_w;
                const float y1 = (bb.y - 0.5f * bb.w) * img_h;
                const float x2 = (bb.x + 0.5f * bb.z) * img_w;
                const float y2 = (bb.y + 0.5f * bb.w) * img_h;
                lmax = fmaxf(lmax, fmaxf(fmaxf(x1, y1), fmaxf(x2, y2)));
            }
        }
        for (int off = 32; off >= 1; off >>= 1)
            lmax = fmaxf(lmax, __shfl_xor(lmax, off, 64));
        if (lane == 0) sRedF[wid] = lmax;
        if (tid == 0) sE2 = above < E2CAND ? above : E2CAND;
        __syncthreads();
        if (tid == 0) {
            float mm = sRedF[0];
            for (int k2 = 1; k2 < NWAVES; ++k2) mm = fmaxf(mm, sRedF[k2]);
            sBmax = mm;
        }
        // ---- sorted-prefix extent E2 (contiguous coverage from 0) ----
        {
            const int bks[2] = { 2 * tid, 2 * tid + 1 };
            #pragma unroll
            for (int q = 0; q < 2; ++q) {
                const int bk = bks[q];
                if (bk > B && sHist[bk] > 0 && sScan[bk] < E2CAND &&
                    sScan[bk] + sHist[bk] > TCAP)
                    atomicMin(&sE2, sScan[bk]);
            }
        }
        __syncthreads();
        const int E2 = sE2;
        {   // mark eligible bins (start < E2 implies end <= TCAP)
            const int bks[2] = { 2 * tid, 2 * tid + 1 };
            #pragma unroll
            for (int q = 0; q < 2; ++q) {
                const int bk = bks[q];
                if (bk > B && sHist[bk] > 0 && sScan[bk] < E2) sHist[bk] |= ELIG;
            }
        }
        __syncthreads();
        // ---- scatter eligible pool keys into sTop (cursor = sScan atomic) ----
        for (int p = tid; p < cnt; p += NT) {
            const unsigned long long k = sPool[p];
            const int bk = bin_of_key(k);
            if (sHist[bk] & ELIG) {
                const int pos = atomicAdd(&sScan[bk], 1);
                if (pos < TCAP) sTop[pos] = k;
            }
        }
        __syncthreads();
        // ---- in-bin rank of sTop positions [0, E2) ----
        {
            unsigned long long k = 0ULL; int dst = -1;
            if (tid < E2) {
                k = sTop[tid];
                const int bk = bin_of_key(k);
                const int len = sHist[bk] & LENMASK;
                const int s0 = sScan[bk] - len;      // cursor - len = bin start
                int r2 = 0;
                for (int q = 0; q < len; ++q) r2 += (sTop[s0 + q] > k) ? 1 : 0;
                dst = s0 + r2;
            }
            __syncthreads();
            if (dst >= 0) sTop[dst] = k;
        }
        __syncthreads();
    }

    __syncthreads();
    bad = sFlag;
    if (bad) {
        // ======== exact fallback (never taken for sane inputs) ========
        unsigned long long lo = 0, hi = (1ULL << 49) - 1;
        while (lo < hi) {
            const unsigned long long mid = lo + ((hi - lo + 1) >> 1);
            int c = 0;
            for (int j = tid; j < NF4; j += NT) {
                const float4 v = ((const float4*)lg)[j];
                const float zv[4] = { v.x, v.y, v.z, v.w };
                #pragma unroll
                for (int q = 0; q < 4; ++q)
                    c += (make_key(mono_u(zv[q]), 4 * j + q) >= mid) ? 1 : 0;
            }
            for (int off = 32; off >= 1; off >>= 1) c += __shfl_xor(c, off, 64);
            if (lane == 0) sWTot[wid] = c;
            __syncthreads();
            if (tid == 0) {
                int a = 0;
                for (int w = 0; w < NWAVES; ++w) a += sWTot[w];
                sPos = a;
            }
            __syncthreads();
            if (sPos >= PRE_TOPK) lo = mid; else hi = mid - 1;
            __syncthreads();
        }
        if (tid == 0) sPos = 0;
        __syncthreads();
        for (int j = tid; j < NF4; j += NT) {
            const float4 v = ((const float4*)lg)[j];
            const float zv[4] = { v.x, v.y, v.z, v.w };
            #pragma unroll
            for (int q = 0; q < 4; ++q) {
                const unsigned long long k = make_key(mono_u(zv[q]), 4 * j + q);
                const bool cand = k >= lo;           // exactly 10000 (keys distinct)
                const unsigned long long mask = __ballot(cand);
                int pos = 0;
                if (lane == 0 && mask) pos = atomicAdd(&sPos, __popcll(mask));
                pos = __shfl(pos, 0, 64);
                if (cand) sPool[pos + __popcll(mask & laneLT)] = k;
            }
        }
        __syncthreads();
        {   // full rank sort of 10000 (slow, correct)
            unsigned long long stash[10]; int spp[10]; int ns = 0;
            for (int p = tid; p < PRE_TOPK; p += NT) {
                const unsigned long long k = sPool[p];
                int r = 0;
                for (int q = 0; q < PRE_TOPK; ++q) r += (sPool[q] > k) ? 1 : 0;
                if (ns < 10) { stash[ns] = k; spp[ns] = r; ++ns; }
            }
            __syncthreads();
            for (int q = 0; q < ns; ++q) sPool[spp[q]] = stash[q];
        }
        __syncthreads();
        float lmax = -3.4e38f;
        for (int p = tid; p < PRE_TOPK; p += NT) {
            const int i = 131071 - (int)(sPool[p] & 0x1FFFFULL);
            const int bi = i / NC;
            const float4 bb = ((const float4*)bx)[bi];
            const float x1 = (bb.x - 0.5f * bb.z) * img_w;
            const float y1 = (bb.y - 0.5f * bb.w) * img_h;
            const float x2 = (bb.x + 0.5f * bb.z) * img_w;
            const float y2 = (bb.y + 0.5f * bb.w) * img_h;
            lmax = fmaxf(lmax, fmaxf(fmaxf(x1, y1), fmaxf(x2, y2)));
        }
        for (int off = 32; off >= 1; off >>= 1)
            lmax = fmaxf(lmax, __shfl_xor(lmax, off, 64));
        if (lane == 0) sRedF[wid] = lmax;
        __syncthreads();
        if (tid == 0) {
            float mm = sRedF[0];
            for (int k2 = 1; k2 < NWAVES; ++k2) mm = fmaxf(mm, sRedF[k2]);
            sBmax = mm;
            sLin = 1;
        }
        __syncthreads();
    }

    const float offc = sBmax + 1.0f;   // labels * (boxes.max() + 1)
    const int E2 = sE2;
    const int lin = sLin;

    // ---- sorted-scan NMS (wave 0) ----
    if (wid == 0) {
        int kept = 0;
        unsigned long long lazyPrev = ~0ULL;
        int lazyInit = 0;
        for (int base = 0; base < PRE_TOPK && kept < TOPK; base += 64) {
            if (!lin) {   // lazy extraction for positions [E2, above) in this chunk
                const int lo2 = base > E2 ? base : E2;
                const int hi2 = (base + 64 < above) ? base + 64 : above;
                if (lo2 < hi2) {
                    if (!lazyInit) {
                        lazyPrev = (E2 > 0) ? sTop[E2 - 1] : ~0ULL;
                        lazyInit = 1;
                    }
                    for (int p = lo2; p < hi2; ++p) {
                        unsigned long long best = 0ULL;
                        for (int off = lane; off < cnt; off += 64) {
                            const unsigned long long k2 = sPool[off];
                            if (k2 < lazyPrev && k2 > best) best = k2;
                        }
                        for (int off = 32; off >= 1; off >>= 1) {
                            const unsigned long long o = __shfl_xor(best, off, 64);
                            best = o > best ? o : best;
                        }
                        if (lane == 0) sLazy[p - base] = best;
                        lazyPrev = best;
                    }
                }
            }
            const int c = base + lane;
            const bool valid = c < PRE_TOPK;
            unsigned long long k = 0ULL;
            if (valid) {
                if (lin)             k = sPool[c];
                else if (c < E2)     k = sTop[c];
                else if (c >= above) k = sBinB[c - above];
                else                 k = sLazy[c - base];
            }
            const int i = valid ? (131071 - (int)(k & 0x1FFFFULL)) : 0;
            const int bi = i / NC, l = i - bi * NC;
            const float4 bb = ((const float4*)bx)[bi];
            const float bx1 = (bb.x - 0.5f * bb.z) * img_w;
            const float by1 = (bb.y - 0.5f * bb.w) * img_h;
            const float bx2 = (bb.x + 0.5f * bb.z) * img_w;
            const float by2 = (bb.y + 0.5f * bb.w) * img_h;
            const float o = (float)l * offc;
            const float ox1 = bx1 + o, oy1 = by1 + o, ox2 = bx2 + o, oy2 = by2 + o;
            const float ar = (ox2 - ox1) * (oy2 - oy1);
            bool alive = valid;
            for (int jj = 0; jj < kept; ++jj) {
                float iw = fminf(sKx2[jj], ox2) - fmaxf(sKx1[jj], ox1);
                float ih = fminf(sKy2[jj], oy2) - fmaxf(sKy1[jj], oy1);
                iw = fmaxf(iw, 0.f); ih = fmaxf(ih, 0.f);
                const float inter = iw * ih;
                if (inter > IOU_THR * (sKa[jj] + ar - inter)) alive = false;
            }
            unsigned long long mask = __ballot(alive);
            while (mask != 0ULL && kept < TOPK) {
                const int s = __ffsll((unsigned long long)mask) - 1;
                const float px1 = __shfl(ox1, s, 64);
                const float py1 = __shfl(oy1, s, 64);
                const float px2 = __shfl(ox2, s, 64);
                const float py2 = __shfl(oy2, s, 64);
                const float pa  = __shfl(ar,  s, 64);
                if (lane == s) {
                    sKx1[kept] = ox1; sKy1[kept] = oy1; sKx2[kept] = ox2; sKy2[kept] = oy2; sKa[kept] = ar;
                    const int oi = b * TOPK + kept;
                    const float z = inv_mono((unsigned int)(k >> 17));
                    const float sc = 1.0f / (1.0f + expf(-z));
                    out[oi] = sc;
                    out[BS * TOPK + oi] = (float)l;
                    out[2 * BS * TOPK + oi * 4 + 0] = bx1;
                    out[2 * BS * TOPK + oi * 4 + 1] = by1;
                    out[2 * BS * TOPK + oi * 4 + 2] = bx2;
                    out[2 * BS * TOPK + oi * 4 + 3] = by2;
                    if (kept == 0) { sFirst[0] = sc; sFirst[1] = (float)l;
                                     sFirst[2] = bx1; sFirst[3] = by1;
                                     sFirst[4] = bx2; sFirst[5] = by2; }
                }
                ++kept;
                if (alive) {
                    float iw = fminf(px2, ox2) - fmaxf(px1, ox1);
                    float ih = fminf(py2, oy2) - fmaxf(py1, oy1);
                    iw = fmaxf(iw, 0.f); ih = fmaxf(ih, 0.f);
                    const float inter = iw * ih;
                    if (inter > IOU_THR * (pa + ar - inter)) alive = false;
                }
                mask = __ballot(alive);
            }
        }
        if (lane == 0) sKept = kept;
    }
    __syncthreads();
    // exhaustion: ref's argmax over all -inf -> index 0 -> replicate row 0
    for (int t = sKept + tid; t < TOPK; t += NT) {
        const int oi = b * TOPK + t;
        out[oi] = sFirst[0];
        out[BS * TOPK + oi] = sFirst[1];
        out[2 * BS * TOPK + oi * 4 + 0] = sFirst[2];
        out[2 * BS * TOPK + oi * 4 + 1] = sFirst[3];
        out[2 * BS * TOPK + oi * 4 + 2] = sFirst[4];
        out[2 * BS * TOPK + oi * 4 + 3] = sFirst[5];
    }
}

extern "C" void kernel_launch(void* const* d_in, const int* in_sizes, int n_in,
                              void* d_out, int out_size, void* d_ws, size_t ws_size,
                              hipStream_t stream) {
    const float* logits = (const float*)d_in[0];   // (8, 900, 91) fp32
    const float* pboxes = (const float*)d_in[1];   // (8, 900, 4) fp32
    const float* ts     = (const float*)d_in[2];   // (8, 2) fp32
    if (ws_size >= WS_REQ) {
        hipLaunchKernelGGL(k1_hist_pool, dim3(NSL, BS), dim3(K1T), 0, stream,
                           logits, d_ws);
        hipLaunchKernelGGL(k2_select_nms, dim3(BS), dim3(NT), 0, stream,
                           logits, pboxes, ts, (float*)d_out, d_ws, 0);
    } else {
        // no workspace: exact in-kernel fallback path (slow, correct)
        hipLaunchKernelGGL(k2_select_nms, dim3(BS), dim3(NT), 0, stream,
                           logits, pboxes, ts, (float*)d_out, d_ws, 1);
    }
}

// Round 8
// 114.200 us; speedup vs baseline: 1.0010x; 1.0010x over previous
//
#include <hip/hip_runtime.h>
#include <cstdint>
#include <cstddef>

#define NQ 900
#define NC 91
#define NFLAT (NQ * NC)        // 81900
#define NF4 (NFLAT / 4)        // 20475
#define BS 8
#define PRE_TOPK 10000
#define TOPK 100
#define IOU_THR 0.7f
#define NT 1024
#define NWAVES 16
#define HB 2048                // bins on z over [-4,4)
#define BINGUESS 1280          // bin_of(1.0): pool = z >= 1.0 (~13K of 81.9K)
#define WCAP 960               // per-wave pool cap (exp 813, +5.6 sigma)
#define POOLSZ (NWAVES * WCAP) // 15360
#define TCAP 512               // sorted-top region capacity
#define E2CAND 256             // sorted prefix target = bitmap candidate count
#define NCAND 256
#define BBCAP 512              // crossing-bin capacity (exp ~64)
#define ELIG 0x40000000
#define LENMASK 0x3FFFFFFF

// sigmoid monotone => order on raw logit z == order on prob.
__device__ __forceinline__ unsigned int mono_u(float z) {
    unsigned int b = __float_as_uint(z);
    return b ^ ((unsigned int)((int)b >> 31) | 0x80000000u);
}
__device__ __forceinline__ float inv_mono(unsigned int u) {
    unsigned int b = (u & 0x80000000u) ? (u ^ 0x80000000u) : ~u;
    return __uint_as_float(b);
}
// 49-bit distinct key == lax.top_k order (score desc, idx asc)
__device__ __forceinline__ unsigned long long make_key(unsigned int u, int i) {
    return ((unsigned long long)u << 17) | (unsigned long long)(131071 - i);
}
__device__ __forceinline__ int bin_of(float z) {
    float t = (z + 4.0f) * 256.0f;
    t = fmaxf(t, 0.0f); t = fminf(t, 2047.0f);
    return (int)t;
}
__device__ __forceinline__ int bin_of_key(unsigned long long k) {
    return bin_of(inv_mono((unsigned int)(k >> 17)));
}

extern "C" __global__ __launch_bounds__(NT)
void NMSPostProcess_70463233458602_kernel(const float* __restrict__ logits,
                                          const float* __restrict__ pboxes,
                                          const float* __restrict__ tsizes,
                                          float* __restrict__ out) {
    __shared__ unsigned long long sPool[POOLSZ];      // 120 KB
    __shared__ unsigned long long sSupScan[HB / 2];   // 8 KB union: sScan / sSup
    __shared__ int sHist[HB];                         // 8 KB
    __shared__ unsigned long long sTop[TCAP];         // 4 KB sorted top prefix
    __shared__ unsigned long long sBinB[BBCAP];       // 4 KB crossing bin
    __shared__ float sOx1[NCAND], sOy1[NCAND], sOx2[NCAND], sOy2[NCAND], sOar[NCAND];
    __shared__ unsigned long long sKeepW[4];
    __shared__ int sKeepPos[TOPK];
    __shared__ float sKx1[TOPK], sKy1[TOPK], sKx2[TOPK], sKy2[TOPK], sKa[TOPK];
    __shared__ float sFirst[6];
    __shared__ float sRedF[NWAVES];
    __shared__ int sWTot[NWAVES], sWSuf[NWAVES], sWCnt[NWAVES];
    __shared__ int sFlag, sB, sRem, sAbove, sKept, sBinBCnt, sPos, sE2, sNK;
    __shared__ unsigned long long sT;
    __shared__ float sBmax;
    int* const sScan = (int*)sSupScan;               // lifetime: scan..in-bin-rank
    unsigned long long* const sSup = sSupScan;       // lifetime: bitmap..scan-NMS

    const int b = blockIdx.x;
    const int tid = threadIdx.x;
    const int wid = tid >> 6, lane = tid & 63;
    const float* lg = logits + (size_t)b * NFLAT;
    const float* bx = pboxes + (size_t)b * NQ * 4;
    const float img_h = tsizes[b * 2 + 0], img_w = tsizes[b * 2 + 1];
    const unsigned long long laneLT = (1ULL << lane) - 1ULL;
    const int wBase = wid * WCAP;

    sHist[tid] = 0; sHist[tid + NT] = 0;
    if (tid == 0) { sFlag = 0; sBinBCnt = 0; sPos = 0; sKept = 0; sB = -1;
                    sAbove = 0; sRem = 1; sE2 = 0; sNK = 0; }
    __syncthreads();

    // ---- pass A: pool-append only (no histogram); candidate = z >= 1.0 ----
    {
        int wCnt = 0;
        #pragma unroll 2
        for (int j = tid; j < NF4; j += NT) {
            const float4 v = ((const float4*)lg)[j];
            const bool c0 = v.x >= 1.0f, c1 = v.y >= 1.0f,
                       c2 = v.z >= 1.0f, c3 = v.w >= 1.0f;
            const unsigned long long m0 = __ballot(c0), m1 = __ballot(c1),
                                     m2 = __ballot(c2), m3 = __ballot(c3);
            const int p0 = __popcll(m0), p1 = __popcll(m1), p2 = __popcll(m2);
            if (c0) { const int o = wCnt + __popcll(m0 & laneLT);
                      if (o < WCAP) sPool[wBase + o] = make_key(mono_u(v.x), 4 * j); }
            if (c1) { const int o = wCnt + p0 + __popcll(m1 & laneLT);
                      if (o < WCAP) sPool[wBase + o] = make_key(mono_u(v.y), 4 * j + 1); }
            if (c2) { const int o = wCnt + p0 + p1 + __popcll(m2 & laneLT);
                      if (o < WCAP) sPool[wBase + o] = make_key(mono_u(v.z), 4 * j + 2); }
            if (c3) { const int o = wCnt + p0 + p1 + p2 + __popcll(m3 & laneLT);
                      if (o < WCAP) sPool[wBase + o] = make_key(mono_u(v.w), 4 * j + 3); }
            wCnt += p0 + p1 + p2 + __popcll(m3);
        }
        if (lane == 0) {
            sWCnt[wid] = wCnt < WCAP ? wCnt : WCAP;
            if (wCnt > WCAP) atomicOr(&sFlag, 1);
        }
    }
    __syncthreads();
    const int myCnt = sWCnt[wid];

    // ---- histogram of the pool (bins < BINGUESS stay 0; never needed) ----
    for (int off = lane; off < myCnt; off += 64)
        atomicAdd(&sHist[bin_of_key(sPool[wBase + off])], 1);
    __syncthreads();

    // ---- shfl hierarchical suffix scan over 2048 bins ----
    {
        const int b0 = 2 * tid, b1 = 2 * tid + 1;
        const int h0 = sHist[b0], h1 = sHist[b1];
        const int s = h0 + h1;
        int v = s;
        #pragma unroll
        for (int off = 1; off < 64; off <<= 1) {
            const int o = __shfl(v, lane + off, 64);
            if (lane + off < 64) v += o;
        }
        if (lane == 0) sWTot[wid] = v;
        __syncthreads();
        if (wid == 0) {
            int t = (lane < NWAVES) ? sWTot[lane] : 0;
            #pragma unroll
            for (int off = 1; off < NWAVES; off <<= 1) {
                const int o = __shfl(t, lane + off, 64);
                if (lane + off < NWAVES) t += o;
            }
            if (lane < NWAVES) sWSuf[lane] = t;
        }
        __syncthreads();
        const int afterWave = sWSuf[wid] - sWTot[wid];
        const int afterPairs = (v - s) + afterWave;
        const int si1 = h1 + afterPairs;
        const int si0 = h0 + si1;
        sScan[b0] = si1;          // exclusive-above = bin start
        sScan[b1] = afterPairs;
        if (si0 >= PRE_TOPK && si1 < PRE_TOPK)        { sB = b0; sAbove = si1;        sRem = PRE_TOPK - si1; }
        if (si1 >= PRE_TOPK && afterPairs < PRE_TOPK) { sB = b1; sAbove = afterPairs; sRem = PRE_TOPK - afterPairs; }
    }
    __syncthreads();
    if (tid == 0 && sB < BINGUESS) sFlag = 1;   // pool must cover the top-10000
    __syncthreads();
    const int B = sB, above = sAbove, rem = sRem;
    int bad = sFlag;

    // ---- collect crossing bin from per-wave pool segments ----
    if (!bad) {
        const int lim = (myCnt + 63) & ~63;
        for (int off = lane; off < lim; off += 64) {
            const bool have = off < myCnt;
            const unsigned long long k = have ? sPool[wBase + off] : 0ULL;
            const bool isB = have && (bin_of_key(k) == B);
            const unsigned long long mask = __ballot(isB);
            const int n = __popcll(mask);
            int base = 0;
            if (lane == 0 && n) base = atomicAdd(&sBinBCnt, n);
            base = __shfl(base, 0, 64);
            if (isB) {
                const int p2 = base + __popcll(mask & laneLT);
                if (p2 < BBCAP) sBinB[p2] = k;
            }
        }
    }
    __syncthreads();
    if (tid == 0 && sBinBCnt > BBCAP) sFlag = 1;
    __syncthreads();
    bad = sFlag;

    if (!bad) {
        // ---- sort crossing bin; T = 10000th key ----
        const int cntB = sBinBCnt;
        unsigned long long kk = 0ULL; int r = -1;
        if (tid < cntB) {
            kk = sBinB[tid]; r = 0;
            for (int q = 0; q < cntB; ++q) r += (sBinB[q] > kk) ? 1 : 0;
        }
        __syncthreads();
        if (r >= 0) sBinB[r] = kk;
        __syncthreads();
        if (tid == 0) sT = sBinB[rem - 1];
    }
    __syncthreads();

    if (!bad) {
        // ---- bmax over exact top-10000 (pool membership: key >= T) ----
        const unsigned long long T = sT;
        float lmax = -3.4e38f;
        for (int off = lane; off < myCnt; off += 64) {
            const unsigned long long k = sPool[wBase + off];
            if (k >= T) {
                const int i = 131071 - (int)(k & 0x1FFFFULL);
                const int bi = i / NC;
                const float4 bb = ((const float4*)bx)[bi];
                const float x1 = (bb.x - 0.5f * bb.z) * img_w;
                const float y1 = (bb.y - 0.5f * bb.w) * img_h;
                const float x2 = (bb.x + 0.5f * bb.z) * img_w;
                const float y2 = (bb.y + 0.5f * bb.w) * img_h;
                lmax = fmaxf(lmax, fmaxf(fmaxf(x1, y1), fmaxf(x2, y2)));
            }
        }
        for (int off = 32; off >= 1; off >>= 1)
            lmax = fmaxf(lmax, __shfl_xor(lmax, off, 64));
        if (lane == 0) sRedF[wid] = lmax;
        if (tid == 0) sE2 = above < E2CAND ? above : E2CAND;
    }
    __syncthreads();
    if (!bad) {
        if (tid == 0) {
            float mm = sRedF[0];
            for (int k2 = 1; k2 < NWAVES; ++k2) mm = fmaxf(mm, sRedF[k2]);
            sBmax = mm;
        }
        // truncate E2 at any bin (start < 256) that would overflow TCAP
        const int bks[2] = { 2 * tid, 2 * tid + 1 };
        #pragma unroll
        for (int q = 0; q < 2; ++q) {
            const int bk = bks[q];
            if (bk > B && sHist[bk] > 0 && sScan[bk] < E2CAND &&
                sScan[bk] + sHist[bk] > TCAP)
                atomicMin(&sE2, sScan[bk]);
        }
    }
    __syncthreads();
    if (!bad) {
        const int E2 = sE2;
        const int bks[2] = { 2 * tid, 2 * tid + 1 };
        #pragma unroll
        for (int q = 0; q < 2; ++q) {
            const int bk = bks[q];
            if (bk > B && sHist[bk] > 0 && sScan[bk] < E2) sHist[bk] |= ELIG;
        }
    }
    __syncthreads();
    if (!bad) {
        // scatter eligible pool keys into sTop (cursor = sScan atomic)
        for (int off = lane; off < myCnt; off += 64) {
            const unsigned long long k = sPool[wBase + off];
            const int bk = bin_of_key(k);
            if (sHist[bk] & ELIG) {
                const int pos = atomicAdd(&sScan[bk], 1);
                if (pos < TCAP) sTop[pos] = k;
            }
        }
    }
    __syncthreads();
    if (!bad) {
        // in-bin rank -> exact sorted positions [0, E2)
        const int E2 = sE2;
        unsigned long long k = 0ULL; int dst = -1;
        if (tid < E2) {
            k = sTop[tid];
            const int bk = bin_of_key(k);
            const int len = sHist[bk] & LENMASK;
            const int s0 = sScan[bk] - len;      // cursor - len = bin start
            int r2 = 0;
            for (int q = 0; q < len; ++q) r2 += (sTop[s0 + q] > k) ? 1 : 0;
            dst = s0 + r2;
        }
        __syncthreads();
        if (dst >= 0) sTop[dst] = k;
    }
    __syncthreads();

    // ---- candidate prep: scaled+offset boxes for first C sorted candidates ----
    const int C = (!bad) ? (sE2 < NCAND ? sE2 : NCAND) : 0;
    if (!bad && tid < C) {
        const unsigned long long k = sTop[tid];
        const int i = 131071 - (int)(k & 0x1FFFFULL);
        const int bi = i / NC, l = i - bi * NC;
        const float4 bb = ((const float4*)bx)[bi];
        const float o = (float)l * (sBmax + 1.0f);
        const float x1 = (bb.x - 0.5f * bb.z) * img_w + o;
        const float y1 = (bb.y - 0.5f * bb.w) * img_h + o;
        const float x2 = (bb.x + 0.5f * bb.z) * img_w + o;
        const float y2 = (bb.y + 0.5f * bb.w) * img_h + o;
        sOx1[tid] = x1; sOy1[tid] = y1; sOx2[tid] = x2; sOy2[tid] = y2;
        sOar[tid] = (x2 - x1) * (y2 - y1);
    }
    __syncthreads();

    // ---- pairwise suppression bitmap (parallel, 1 row-word per thread) ----
    if (!bad) {
        const int r = tid >> 2, w = tid & 3;
        unsigned long long bits = 0ULL;
        if (r < C) {
            const float rx1 = sOx1[r], ry1 = sOy1[r], rx2 = sOx2[r], ry2 = sOy2[r];
            const float ra = sOar[r];
            #pragma unroll 4
            for (int jj = 0; jj < 64; ++jj) {
                const int j = (w << 6) + jj;
                if (j < C) {
                    float iw = fminf(rx2, sOx2[j]) - fmaxf(rx1, sOx1[j]);
                    float ih = fminf(ry2, sOy2[j]) - fmaxf(ry1, sOy1[j]);
                    iw = fmaxf(iw, 0.f); ih = fmaxf(ih, 0.f);
                    const float inter = iw * ih;
                    if (inter > IOU_THR * (ra + sOar[j] - inter)) bits |= 1ULL << jj;
                }
            }
        }
        sSup[(r << 2) | w] = bits;   // row r, word w: who row-r suppresses
    }
    __syncthreads();

    // ---- bitmap scan (wave 0): per-step chain is register-only ----
    if (!bad && wid == 0) {
        unsigned long long live = 0ULL;
        if (lane < 4) {
            const int n = C - (lane << 6);
            live = (n >= 64) ? ~0ULL : ((n <= 0) ? 0ULL : ((1ULL << n) - 1ULL));
        }
        unsigned long long keepW = 0ULL;
        int kept = 0;
        const int myw = lane & 3;
        for (int ch = 0; ch < 4 && kept < TOPK; ++ch) {
            unsigned long long cur = __shfl(live, ch, 64);  // word ch, replicated
            unsigned long long acc = 0ULL;
            #pragma unroll 8
            for (int bit = 0; bit < 64; ++bit) {
                const int i = (ch << 6) | bit;
                const unsigned long long rowC = sSup[(i << 2) | ch];
                const unsigned long long rowM = sSup[(i << 2) | myw];
                if ((cur >> bit) & 1ULL) {                  // wave-uniform
                    cur &= ~rowC;
                    acc |= rowM;
                    if (lane == ch) keepW |= 1ULL << bit;
                }
            }
            if (lane < 4) live &= ~acc;
            int c = __popcll(keepW);
            for (int off = 32; off >= 1; off >>= 1) c += __shfl_xor(c, off, 64);
            kept = c;
        }
        if (lane < 4) sKeepW[lane] = keepW;
        if (lane == 0) sNK = kept;
    }
    __syncthreads();
    if (tid == 0 && !bad && sNK < TOPK) sFlag = 1;   // exhausted 256 cands -> exact path
    __syncthreads();
    bad = sFlag;

    if (!bad) {
        // keep list: first TOPK set bits in order
        if (tid < C) {
            const int w = tid >> 6;
            const unsigned long long m = sKeepW[w];
            if ((m >> (tid & 63)) & 1ULL) {
                int rank = __popcll(m & ((1ULL << (tid & 63)) - 1ULL));
                for (int ww = 0; ww < w; ++ww) rank += __popcll(sKeepW[ww]);
                if (rank < TOPK) sKeepPos[rank] = tid;
            }
        }
    }
    __syncthreads();
    if (!bad) {
        // parallel outputs (incl. all sigmoids)
        if (tid < TOPK) {
            const int p = sKeepPos[tid];
            const unsigned long long k = sTop[p];
            const int i = 131071 - (int)(k & 0x1FFFFULL);
            const int bi = i / NC, l = i - bi * NC;
            const float4 bb = ((const float4*)bx)[bi];
            const float bx1 = (bb.x - 0.5f * bb.z) * img_w;
            const float by1 = (bb.y - 0.5f * bb.w) * img_h;
            const float bx2 = (bb.x + 0.5f * bb.z) * img_w;
            const float by2 = (bb.y + 0.5f * bb.w) * img_h;
            const float z = inv_mono((unsigned int)(k >> 17));
            const int oi = b * TOPK + tid;
            out[oi] = 1.0f / (1.0f + expf(-z));
            out[BS * TOPK + oi] = (float)l;
            out[2 * BS * TOPK + oi * 4 + 0] = bx1;
            out[2 * BS * TOPK + oi * 4 + 1] = by1;
            out[2 * BS * TOPK + oi * 4 + 2] = bx2;
            out[2 * BS * TOPK + oi * 4 + 3] = by2;
        }
        if (tid == 0) sKept = TOPK;
    }
    __syncthreads();

    if (bad) {
        // ======== exact fallback (never taken for sane inputs) ========
        unsigned long long lo = 0, hi = (1ULL << 49) - 1;
        while (lo < hi) {
            const unsigned long long mid = lo + ((hi - lo + 1) >> 1);
            int c = 0;
            for (int j = tid; j < NF4; j += NT) {
                const float4 v = ((const float4*)lg)[j];
                const float zv[4] = { v.x, v.y, v.z, v.w };
                #pragma unroll
                for (int q = 0; q < 4; ++q)
                    c += (make_key(mono_u(zv[q]), 4 * j + q) >= mid) ? 1 : 0;
            }
            for (int off = 32; off >= 1; off >>= 1) c += __shfl_xor(c, off, 64);
            if (lane == 0) sWTot[wid] = c;
            __syncthreads();
            if (tid == 0) {
                int a = 0;
                for (int w = 0; w < NWAVES; ++w) a += sWTot[w];
                sPos = a;
            }
            __syncthreads();
            if (sPos >= PRE_TOPK) lo = mid; else hi = mid - 1;
            __syncthreads();
        }
        if (tid == 0) sPos = 0;
        __syncthreads();
        for (int j = tid; j < NF4; j += NT) {
            const float4 v = ((const float4*)lg)[j];
            const float zv[4] = { v.x, v.y, v.z, v.w };
            #pragma unroll
            for (int q = 0; q < 4; ++q) {
                const unsigned long long k = make_key(mono_u(zv[q]), 4 * j + q);
                const bool cand = k >= lo;        // exactly 10000 (keys distinct)
                const unsigned long long mask = __ballot(cand);
                int pos = 0;
                if (lane == 0 && mask) pos = atomicAdd(&sPos, __popcll(mask));
                pos = __shfl(pos, 0, 64);
                if (cand) sPool[pos + __popcll(mask & laneLT)] = k;
            }
        }
        __syncthreads();
        {   // full rank sort of 10000 (slow, correct)
            unsigned long long stash[10]; int spp[10]; int ns = 0;
            for (int p = tid; p < PRE_TOPK; p += NT) {
                const unsigned long long k = sPool[p];
                int r = 0;
                for (int q = 0; q < PRE_TOPK; ++q) r += (sPool[q] > k) ? 1 : 0;
                if (ns < 10) { stash[ns] = k; spp[ns] = r; ++ns; }
            }
            __syncthreads();
            for (int q = 0; q < ns; ++q) sPool[spp[q]] = stash[q];
        }
        __syncthreads();
        float lmax = -3.4e38f;
        for (int p = tid; p < PRE_TOPK; p += NT) {
            const int i = 131071 - (int)(sPool[p] & 0x1FFFFULL);
            const int bi = i / NC;
            const float4 bb = ((const float4*)bx)[bi];
            const float x1 = (bb.x - 0.5f * bb.z) * img_w;
            const float y1 = (bb.y - 0.5f * bb.w) * img_h;
            const float x2 = (bb.x + 0.5f * bb.z) * img_w;
            const float y2 = (bb.y + 0.5f * bb.w) * img_h;
            lmax = fmaxf(lmax, fmaxf(fmaxf(x1, y1), fmaxf(x2, y2)));
        }
        for (int off = 32; off >= 1; off >>= 1)
            lmax = fmaxf(lmax, __shfl_xor(lmax, off, 64));
        if (lane == 0) sRedF[wid] = lmax;
        __syncthreads();
        if (tid == 0) {
            float mm = sRedF[0];
            for (int k2 = 1; k2 < NWAVES; ++k2) mm = fmaxf(mm, sRedF[k2]);
            sBmax = mm;
        }
        __syncthreads();
        const float offc = sBmax + 1.0f;
        if (wid == 0) {
            int kept = 0;
            for (int base = 0; base < PRE_TOPK && kept < TOPK; base += 64) {
                const int c = base + lane;
                const bool valid = c < PRE_TOPK;
                const unsigned long long k = valid ? sPool[c] : 0ULL;
                const int i = valid ? (131071 - (int)(k & 0x1FFFFULL)) : 0;
                const int bi = i / NC, l = i - bi * NC;
                const float4 bb = ((const float4*)bx)[bi];
                const float bx1 = (bb.x - 0.5f * bb.z) * img_w;
                const float by1 = (bb.y - 0.5f * bb.w) * img_h;
                const float bx2 = (bb.x + 0.5f * bb.z) * img_w;
                const float by2 = (bb.y + 0.5f * bb.w) * img_h;
                const float o = (float)l * offc;
                const float ox1 = bx1 + o, oy1 = by1 + o, ox2 = bx2 + o, oy2 = by2 + o;
                const float ar = (ox2 - ox1) * (oy2 - oy1);
                bool alive = valid;
                for (int jj = 0; jj < kept; ++jj) {
                    float iw = fminf(sKx2[jj], ox2) - fmaxf(sKx1[jj], ox1);
                    float ih = fminf(sKy2[jj], oy2) - fmaxf(sKy1[jj], oy1);
                    iw = fmaxf(iw, 0.f); ih = fmaxf(ih, 0.f);
                    const float inter = iw * ih;
                    if (inter > IOU_THR * (sKa[jj] + ar - inter)) alive = false;
                }
                unsigned long long mask = __ballot(alive);
                while (mask != 0ULL && kept < TOPK) {
                    const int s = __ffsll((unsigned long long)mask) - 1;
                    const float px1 = __shfl(ox1, s, 64);
                    const float py1 = __shfl(oy1, s, 64);
                    const float px2 = __shfl(ox2, s, 64);
                    const float py2 = __shfl(oy2, s, 64);
                    const float pa  = __shfl(ar,  s, 64);
                    if (lane == s) {
                        sKx1[kept] = ox1; sKy1[kept] = oy1; sKx2[kept] = ox2;
                        sKy2[kept] = oy2; sKa[kept] = ar;
                        const int oi = b * TOPK + kept;
                        const float z = inv_mono((unsigned int)(k >> 17));
                        const float sc = 1.0f / (1.0f + expf(-z));
                        out[oi] = sc;
                        out[BS * TOPK + oi] = (float)l;
                        out[2 * BS * TOPK + oi * 4 + 0] = bx1;
                        out[2 * BS * TOPK + oi * 4 + 1] = by1;
                        out[2 * BS * TOPK + oi * 4 + 2] = bx2;
                        out[2 * BS * TOPK + oi * 4 + 3] = by2;
                        if (kept == 0) { sFirst[0] = sc; sFirst[1] = (float)l;
                                         sFirst[2] = bx1; sFirst[3] = by1;
                                         sFirst[4] = bx2; sFirst[5] = by2; }
                    }
                    ++kept;
                    if (alive) {
                        float iw = fminf(px2, ox2) - fmaxf(px1, ox1);
                        float ih = fminf(py2, oy2) - fmaxf(py1, oy1);
                        iw = fmaxf(iw, 0.f); ih = fmaxf(ih, 0.f);
                        const float inter = iw * ih;
                        if (inter > IOU_THR * (pa + ar - inter)) alive = false;
                    }
                    mask = __ballot(alive);
                }
            }
            if (lane == 0) sKept = kept;
        }
        __syncthreads();
    }

    // exhaustion: ref's argmax over all -inf -> index 0 -> replicate row 0
    for (int t = sKept + tid; t < TOPK; t += NT) {
        const int oi = b * TOPK + t;
        out[oi] = sFirst[0];
        out[BS * TOPK + oi] = sFirst[1];
        out[2 * BS * TOPK + oi * 4 + 0] = sFirst[2];
        out[2 * BS * TOPK + oi * 4 + 1] = sFirst[3];
        out[2 * BS * TOPK + oi * 4 + 2] = sFirst[4];
        out[2 * BS * TOPK + oi * 4 + 3] = sFirst[5];
    }
}

extern "C" void kernel_launch(void* const* d_in, const int* in_sizes, int n_in,
                              void* d_out, int out_size, void* d_ws, size_t ws_size,
                              hipStream_t stream) {
    const float* logits = (const float*)d_in[0];   // (8, 900, 91) fp32
    const float* pboxes = (const float*)d_in[1];   // (8, 900, 4) fp32
    const float* ts     = (const float*)d_in[2];   // (8, 2) fp32
    hipLaunchKernelGGL(NMSPostProcess_70463233458602_kernel,
                       dim3(BS), dim3(NT), 0, stream,
                       logits, pboxes, ts, (float*)d_out);
}

// Round 9
// 103.163 us; speedup vs baseline: 1.1081x; 1.1070x over previous
//
#include <hip/hip_runtime.h>
#include <cstdint>
#include <cstddef>

#define NQ 900
#define NC 91
#define NFLAT (NQ * NC)        // 81900
#define NF4 (NFLAT / 4)        // 20475
#define BS 8
#define PRE_TOPK 10000
#define TOPK 100
#define IOU_THR 0.7f
#define NT 1024
#define NWAVES 16
#define HB 2048                // bins on z over [-4,4)
#define BINGUESS 1280          // bin_of(1.0): pool = z >= 1.0 (~13K of 81.9K)
#define WCAP 960               // per-wave pool cap (exp 813, +5.6 sigma)
#define POOLSZ (NWAVES * WCAP) // 15360
#define TCAP 512               // sorted-top region capacity
#define E2CAND 256             // sorted prefix target = bitmap candidate count
#define NCAND 256
#define BBCAP 512              // crossing-bin capacity (exp ~64)
#define ELIG 0x40000000
#define LENMASK 0x3FFFFFFF

// sigmoid monotone => order on raw logit z == order on prob.
__device__ __forceinline__ unsigned int mono_u(float z) {
    unsigned int b = __float_as_uint(z);
    return b ^ ((unsigned int)((int)b >> 31) | 0x80000000u);
}
__device__ __forceinline__ float inv_mono(unsigned int u) {
    unsigned int b = (u & 0x80000000u) ? (u ^ 0x80000000u) : ~u;
    return __uint_as_float(b);
}
// 49-bit distinct key == lax.top_k order (score desc, idx asc)
__device__ __forceinline__ unsigned long long make_key(unsigned int u, int i) {
    return ((unsigned long long)u << 17) | (unsigned long long)(131071 - i);
}
__device__ __forceinline__ int bin_of(float z) {
    float t = (z + 4.0f) * 256.0f;
    t = fmaxf(t, 0.0f); t = fminf(t, 2047.0f);
    return (int)t;
}
__device__ __forceinline__ int bin_of_key(unsigned long long k) {
    return bin_of(inv_mono((unsigned int)(k >> 17)));
}

extern "C" __global__ __launch_bounds__(NT)
void NMSPostProcess_70463233458602_kernel(const float* __restrict__ logits,
                                          const float* __restrict__ pboxes,
                                          const float* __restrict__ tsizes,
                                          float* __restrict__ out) {
    __shared__ unsigned long long sPool[POOLSZ];      // 120 KB
    __shared__ unsigned long long sSupScan[HB / 2];   // 8 KB union: sScan / sSup
    __shared__ int sHist[HB];                         // 8 KB
    __shared__ unsigned long long sTop[TCAP];         // 4 KB sorted top prefix
    __shared__ unsigned long long sBinB[BBCAP];       // 4 KB crossing bin
    __shared__ float4 sOB[NCAND];                     // 4 KB obox (x1,y1,x2,y2)
    __shared__ float sOar[NCAND];                     // 1 KB obox area
    __shared__ unsigned char sFlagB[1024];            // 1 KB per-box top-10000 flag
    __shared__ unsigned long long sKeepW[4];
    __shared__ int sKeepPos[TOPK];
    __shared__ float sKx1[TOPK], sKy1[TOPK], sKx2[TOPK], sKy2[TOPK], sKa[TOPK];
    __shared__ float sFirst[6];
    __shared__ float sRedF[NWAVES];
    __shared__ int sWTot[NWAVES], sWSuf[NWAVES], sWCnt[NWAVES];
    __shared__ int sFlag, sB, sRem, sAbove, sKept, sBinBCnt, sPos, sE2, sNK;
    __shared__ float sBmax;
    int* const sScan = (int*)sSupScan;               // lifetime: scan .. in-bin-rank
    unsigned long long* const sSup = sSupScan;       // lifetime: bitmap .. scan-NMS

    const int b = blockIdx.x;
    const int tid = threadIdx.x;
    const int wid = tid >> 6, lane = tid & 63;
    const float* lg = logits + (size_t)b * NFLAT;
    const float* bx = pboxes + (size_t)b * NQ * 4;
    const float img_h = tsizes[b * 2 + 0], img_w = tsizes[b * 2 + 1];
    const unsigned long long laneLT = (1ULL << lane) - 1ULL;
    const int wBase = wid * WCAP;

    sHist[tid] = 0; sHist[tid + NT] = 0;
    sFlagB[tid & 1023] = 0;
    if (tid == 0) { sFlag = 0; sBinBCnt = 0; sPos = 0; sKept = 0; sB = -1;
                    sAbove = 0; sRem = 1; sE2 = 0; sNK = 0; }
    __syncthreads();

    // ---- pass A: pool append + pool histogram (candidate = z >= 1.0) ----
    {
        int wCnt = 0;
        #pragma unroll 2
        for (int j = tid; j < NF4; j += NT) {
            const float4 v = ((const float4*)lg)[j];
            const bool c0 = v.x >= 1.0f, c1 = v.y >= 1.0f,
                       c2 = v.z >= 1.0f, c3 = v.w >= 1.0f;
            const unsigned long long m0 = __ballot(c0), m1 = __ballot(c1),
                                     m2 = __ballot(c2), m3 = __ballot(c3);
            const int p0 = __popcll(m0), p1 = __popcll(m1), p2 = __popcll(m2);
            if (c0) { const int o = wCnt + __popcll(m0 & laneLT);
                      if (o < WCAP) sPool[wBase + o] = make_key(mono_u(v.x), 4 * j);
                      atomicAdd(&sHist[bin_of(v.x)], 1); }
            if (c1) { const int o = wCnt + p0 + __popcll(m1 & laneLT);
                      if (o < WCAP) sPool[wBase + o] = make_key(mono_u(v.y), 4 * j + 1);
                      atomicAdd(&sHist[bin_of(v.y)], 1); }
            if (c2) { const int o = wCnt + p0 + p1 + __popcll(m2 & laneLT);
                      if (o < WCAP) sPool[wBase + o] = make_key(mono_u(v.z), 4 * j + 2);
                      atomicAdd(&sHist[bin_of(v.z)], 1); }
            if (c3) { const int o = wCnt + p0 + p1 + p2 + __popcll(m3 & laneLT);
                      if (o < WCAP) sPool[wBase + o] = make_key(mono_u(v.w), 4 * j + 3);
                      atomicAdd(&sHist[bin_of(v.w)], 1); }
            wCnt += p0 + p1 + p2 + __popcll(m3);
        }
        if (lane == 0) {
            sWCnt[wid] = wCnt < WCAP ? wCnt : WCAP;
            if (wCnt > WCAP) atomicOr(&sFlag, 1);
        }
    }
    __syncthreads();
    const int myCnt = sWCnt[wid];

    // ---- shfl hierarchical suffix scan over 2048 bins ----
    {
        const int b0 = 2 * tid, b1 = 2 * tid + 1;
        const int h0 = sHist[b0], h1 = sHist[b1];
        const int s = h0 + h1;
        int v = s;
        #pragma unroll
        for (int off = 1; off < 64; off <<= 1) {
            const int o = __shfl(v, lane + off, 64);
            if (lane + off < 64) v += o;
        }
        if (lane == 0) sWTot[wid] = v;
        __syncthreads();
        if (wid == 0) {
            int t = (lane < NWAVES) ? sWTot[lane] : 0;
            #pragma unroll
            for (int off = 1; off < NWAVES; off <<= 1) {
                const int o = __shfl(t, lane + off, 64);
                if (lane + off < NWAVES) t += o;
            }
            if (lane < NWAVES) sWSuf[lane] = t;
        }
        __syncthreads();
        const int afterWave = sWSuf[wid] - sWTot[wid];
        const int afterPairs = (v - s) + afterWave;
        const int si1 = h1 + afterPairs;
        const int si0 = h0 + si1;
        sScan[b0] = si1;          // exclusive-above = bin start
        sScan[b1] = afterPairs;
        if (si0 >= PRE_TOPK && si1 < PRE_TOPK)        { sB = b0; sAbove = si1;        sRem = PRE_TOPK - si1; }
        if (si1 >= PRE_TOPK && afterPairs < PRE_TOPK) { sB = b1; sAbove = afterPairs; sRem = PRE_TOPK - afterPairs; }
    }
    __syncthreads();
    if (tid == 0) {
        if (sB < BINGUESS) sFlag = 1;   // pool must cover the top-10000
        sE2 = sAbove < E2CAND ? sAbove : E2CAND;
    }
    __syncthreads();
    const int B = sB, above = sAbove, rem = sRem;
    int bad = sFlag;

    // ---- E2 truncation: any bin (start < 256) whose range would overflow TCAP ----
    if (!bad) {
        const int bks[2] = { 2 * tid, 2 * tid + 1 };
        #pragma unroll
        for (int q = 0; q < 2; ++q) {
            const int bk = bks[q];
            if (bk > B && sHist[bk] > 0 && sScan[bk] < E2CAND &&
                sScan[bk] + sHist[bk] > TCAP)
                atomicMin(&sE2, sScan[bk]);
        }
    }
    __syncthreads();
    if (!bad) {   // mark eligible bins (start < E2 implies end <= TCAP)
        const int E2 = sE2;
        const int bks[2] = { 2 * tid, 2 * tid + 1 };
        #pragma unroll
        for (int q = 0; q < 2; ++q) {
            const int bk = bks[q];
            if (bk > B && sHist[bk] > 0 && sScan[bk] < E2) sHist[bk] |= ELIG;
        }
    }
    __syncthreads();

    // ---- SINGLE pool pass: box flags (bins>B), eligible scatter, bin-B collect ----
    if (!bad) {
        const int lim = (myCnt + 63) & ~63;
        for (int off = lane; off < lim; off += 64) {
            const bool have = off < myCnt;
            const unsigned long long k = have ? sPool[wBase + off] : 0ULL;
            const int bk = have ? bin_of_key(k) : 0;
            if (have && bk > B) {
                const int i = 131071 - (int)(k & 0x1FFFFULL);
                sFlagB[i / NC] = 1;                   // definite top-10000 member
                if (sHist[bk] & ELIG) {
                    const int pos = atomicAdd(&sScan[bk], 1);
                    if (pos < TCAP) sTop[pos] = k;
                }
            }
            const bool isB = have && (bk == B);
            const unsigned long long mask = __ballot(isB);
            const int n = __popcll(mask);
            int base = 0;
            if (lane == 0 && n) base = atomicAdd(&sBinBCnt, n);
            base = __shfl(base, 0, 64);
            if (isB) {
                const int p2 = base + __popcll(mask & laneLT);
                if (p2 < BBCAP) sBinB[p2] = k;
            }
        }
    }
    __syncthreads();
    if (tid == 0 && sBinBCnt > BBCAP) sFlag = 1;
    __syncthreads();
    bad = sFlag;

    // ---- crossing bin: rank; top-rem set box flags (completes top-10000 set) ----
    if (!bad) {
        const int cntB = sBinBCnt;
        if (tid < cntB) {
            const unsigned long long kk = sBinB[tid];
            int r = 0;
            for (int q = 0; q < cntB; ++q) r += (sBinB[q] > kk) ? 1 : 0;
            if (r < rem) {
                const int i = 131071 - (int)(kk & 0x1FFFFULL);
                sFlagB[i / NC] = 1;
            }
        }
    }
    __syncthreads();

    // ---- bmax: max over flagged boxes (exactly the gathered top-10000) ----
    if (!bad) {
        float lmax = -3.4e38f;
        if (tid < NQ && sFlagB[tid]) {
            const float4 bb = ((const float4*)bx)[tid];
            const float x1 = (bb.x - 0.5f * bb.z) * img_w;
            const float y1 = (bb.y - 0.5f * bb.w) * img_h;
            const float x2 = (bb.x + 0.5f * bb.z) * img_w;
            const float y2 = (bb.y + 0.5f * bb.w) * img_h;
            lmax = fmaxf(fmaxf(x1, y1), fmaxf(x2, y2));
        }
        for (int off = 32; off >= 1; off >>= 1)
            lmax = fmaxf(lmax, __shfl_xor(lmax, off, 64));
        if (lane == 0) sRedF[wid] = lmax;
        __syncthreads();
        if (tid == 0) {
            float mm = sRedF[0];
            for (int k2 = 1; k2 < NWAVES; ++k2) mm = fmaxf(mm, sRedF[k2]);
            sBmax = mm;
        }
    }
    __syncthreads();

    // ---- in-bin rank -> exact sorted candidates sTop[0, E2) ----
    if (!bad) {
        const int E2 = sE2;
        unsigned long long k = 0ULL; int dst = -1;
        if (tid < E2) {
            k = sTop[tid];
            const int bk = bin_of_key(k);
            const int len = sHist[bk] & LENMASK;
            const int s0 = sScan[bk] - len;      // cursor - len = bin start
            int r2 = 0;
            for (int q = 0; q < len; ++q) r2 += (sTop[s0 + q] > k) ? 1 : 0;
            dst = s0 + r2;
        }
        __syncthreads();
        if (dst >= 0) sTop[dst] = k;
    }
    __syncthreads();

    // ---- candidate prep: scaled+offset boxes for first C sorted candidates ----
    const int C = (!bad) ? (sE2 < NCAND ? sE2 : NCAND) : 0;
    if (!bad && tid < C) {
        const unsigned long long k = sTop[tid];
        const int i = 131071 - (int)(k & 0x1FFFFULL);
        const int bi = i / NC, l = i - bi * NC;
        const float4 bb = ((const float4*)bx)[bi];
        const float o = (float)l * (sBmax + 1.0f);
        float4 ob;
        ob.x = (bb.x - 0.5f * bb.z) * img_w + o;
        ob.y = (bb.y - 0.5f * bb.w) * img_h + o;
        ob.z = (bb.x + 0.5f * bb.z) * img_w + o;
        ob.w = (bb.y + 0.5f * bb.w) * img_h + o;
        sOB[tid] = ob;
        sOar[tid] = (ob.z - ob.x) * (ob.w - ob.y);
    }
    __syncthreads();

    // ---- suppression bitmap via ballot: wave v -> word w=v&3, rows (v>>2)*64.. ----
    if (!bad) {
        const int w = wid & 3;
        const int r0 = (wid >> 2) << 6;
        const int cj = (w << 6) + lane;          // this lane's column candidate
        const bool cv = cj < C;
        float4 cb = make_float4(0.f, 0.f, 0.f, 0.f);
        float car = 0.f;
        if (cv) { cb = sOB[cj]; car = sOar[cj]; }
        for (int t = 0; t < 64; ++t) {
            const int i = r0 + t;
            unsigned long long bits = 0ULL;
            if (i < C) {
                const float4 rb = sOB[i];        // broadcast
                const float ra = sOar[i];        // broadcast
                bool sup = false;
                if (cv) {
                    float iw = fminf(rb.z, cb.z) - fmaxf(rb.x, cb.x);
                    float ih = fminf(rb.w, cb.w) - fmaxf(rb.y, cb.y);
                    iw = fmaxf(iw, 0.f); ih = fmaxf(ih, 0.f);
                    const float inter = iw * ih;
                    sup = inter > IOU_THR * (ra + car - inter);
                }
                bits = __ballot(sup);
            }
            if (lane == 0) sSup[(i << 2) | w] = bits;   // row i suppresses word w
        }
    }
    __syncthreads();

    // ---- bitmap scan (wave 0): per-step chain is register-only ----
    if (!bad && wid == 0) {
        unsigned long long live = 0ULL;
        if (lane < 4) {
            const int n = C - (lane << 6);
            live = (n >= 64) ? ~0ULL : ((n <= 0) ? 0ULL : ((1ULL << n) - 1ULL));
        }
        unsigned long long keepW = 0ULL;
        int kept = 0;
        const int myw = lane & 3;
        for (int ch = 0; ch < 4 && kept < TOPK; ++ch) {
            unsigned long long cur = __shfl(live, ch, 64);  // word ch, replicated
            unsigned long long acc = 0ULL;
            #pragma unroll 8
            for (int bit = 0; bit < 64; ++bit) {
                const int i = (ch << 6) | bit;
                const unsigned long long rowC = sSup[(i << 2) | ch];
                const unsigned long long rowM = sSup[(i << 2) | myw];
                if ((cur >> bit) & 1ULL) {                  // wave-uniform
                    cur &= ~rowC;
                    acc |= rowM;
                    if (lane == ch) keepW |= 1ULL << bit;
                }
            }
            if (lane < 4) live &= ~acc;
            int c = __popcll(keepW);
            for (int off = 32; off >= 1; off >>= 1) c += __shfl_xor(c, off, 64);
            kept = c;
        }
        if (lane < 4) sKeepW[lane] = keepW;
        if (lane == 0) sNK = kept;
    }
    __syncthreads();
    if (tid == 0 && !bad && sNK < TOPK) sFlag = 1;   // exhausted 256 cands -> exact path
    __syncthreads();
    bad = sFlag;

    if (!bad) {
        // keep list: first TOPK set bits in order
        if (tid < C) {
            const int w = tid >> 6;
            const unsigned long long m = sKeepW[w];
            if ((m >> (tid & 63)) & 1ULL) {
                int rank = __popcll(m & ((1ULL << (tid & 63)) - 1ULL));
                for (int ww = 0; ww < w; ++ww) rank += __popcll(sKeepW[ww]);
                if (rank < TOPK) sKeepPos[rank] = tid;
            }
        }
    }
    __syncthreads();
    if (!bad) {
        // parallel outputs (incl. all sigmoids)
        if (tid < TOPK) {
            const int p = sKeepPos[tid];
            const unsigned long long k = sTop[p];
            const int i = 131071 - (int)(k & 0x1FFFFULL);
            const int bi = i / NC, l = i - bi * NC;
            const float4 bb = ((const float4*)bx)[bi];
            const float bx1 = (bb.x - 0.5f * bb.z) * img_w;
            const float by1 = (bb.y - 0.5f * bb.w) * img_h;
            const float bx2 = (bb.x + 0.5f * bb.z) * img_w;
            const float by2 = (bb.y + 0.5f * bb.w) * img_h;
            const float z = inv_mono((unsigned int)(k >> 17));
            const int oi = b * TOPK + tid;
            out[oi] = 1.0f / (1.0f + expf(-z));
            out[BS * TOPK + oi] = (float)l;
            out[2 * BS * TOPK + oi * 4 + 0] = bx1;
            out[2 * BS * TOPK + oi * 4 + 1] = by1;
            out[2 * BS * TOPK + oi * 4 + 2] = bx2;
            out[2 * BS * TOPK + oi * 4 + 3] = by2;
        }
        if (tid == 0) sKept = TOPK;
    }
    __syncthreads();

    if (bad) {
        // ======== exact fallback (never taken for sane inputs) ========
        unsigned long long lo = 0, hi = (1ULL << 49) - 1;
        while (lo < hi) {
            const unsigned long long mid = lo + ((hi - lo + 1) >> 1);
            int c = 0;
            for (int j = tid; j < NF4; j += NT) {
                const float4 v = ((const float4*)lg)[j];
                const float zv[4] = { v.x, v.y, v.z, v.w };
                #pragma unroll
                for (int q = 0; q < 4; ++q)
                    c += (make_key(mono_u(zv[q]), 4 * j + q) >= mid) ? 1 : 0;
            }
            for (int off = 32; off >= 1; off >>= 1) c += __shfl_xor(c, off, 64);
            if (lane == 0) sWTot[wid] = c;
            __syncthreads();
            if (tid == 0) {
                int a = 0;
                for (int w = 0; w < NWAVES; ++w) a += sWTot[w];
                sPos = a;
            }
            __syncthreads();
            if (sPos >= PRE_TOPK) lo = mid; else hi = mid - 1;
            __syncthreads();
        }
        if (tid == 0) sPos = 0;
        __syncthreads();
        for (int j = tid; j < NF4; j += NT) {
            const float4 v = ((const float4*)lg)[j];
            const float zv[4] = { v.x, v.y, v.z, v.w };
            #pragma unroll
            for (int q = 0; q < 4; ++q) {
                const unsigned long long k = make_key(mono_u(zv[q]), 4 * j + q);
                const bool cand = k >= lo;        // exactly 10000 (keys distinct)
                const unsigned long long mask = __ballot(cand);
                int pos = 0;
                if (lane == 0 && mask) pos = atomicAdd(&sPos, __popcll(mask));
                pos = __shfl(pos, 0, 64);
                if (cand) sPool[pos + __popcll(mask & laneLT)] = k;
            }
        }
        __syncthreads();
        {   // full rank sort of 10000 (slow, correct)
            unsigned long long stash[10]; int spp[10]; int ns = 0;
            for (int p = tid; p < PRE_TOPK; p += NT) {
                const unsigned long long k = sPool[p];
                int r = 0;
                for (int q = 0; q < PRE_TOPK; ++q) r += (sPool[q] > k) ? 1 : 0;
                if (ns < 10) { stash[ns] = k; spp[ns] = r; ++ns; }
            }
            __syncthreads();
            for (int q = 0; q < ns; ++q) sPool[spp[q]] = stash[q];
        }
        __syncthreads();
        float lmax = -3.4e38f;
        for (int p = tid; p < PRE_TOPK; p += NT) {
            const int i = 131071 - (int)(sPool[p] & 0x1FFFFULL);
            const int bi = i / NC;
            const float4 bb = ((const float4*)bx)[bi];
            const float x1 = (bb.x - 0.5f * bb.z) * img_w;
            const float y1 = (bb.y - 0.5f * bb.w) * img_h;
            const float x2 = (bb.x + 0.5f * bb.z) * img_w;
            const float y2 = (bb.y + 0.5f * bb.w) * img_h;
            lmax = fmaxf(lmax, fmaxf(fmaxf(x1, y1), fmaxf(x2, y2)));
        }
        for (int off = 32; off >= 1; off >>= 1)
            lmax = fmaxf(lmax, __shfl_xor(lmax, off, 64));
        if (lane == 0) sRedF[wid] = lmax;
        __syncthreads();
        if (tid == 0) {
            float mm = sRedF[0];
            for (int k2 = 1; k2 < NWAVES; ++k2) mm = fmaxf(mm, sRedF[k2]);
            sBmax = mm;
        }
        __syncthreads();
        const float offc = sBmax + 1.0f;
        if (wid == 0) {
            int kept = 0;
            for (int base = 0; base < PRE_TOPK && kept < TOPK; base += 64) {
                const int c = base + lane;
                const bool valid = c < PRE_TOPK;
                const unsigned long long k = valid ? sPool[c] : 0ULL;
                const int i = valid ? (131071 - (int)(k & 0x1FFFFULL)) : 0;
                const int bi = i / NC, l = i - bi * NC;
                const float4 bb = ((const float4*)bx)[bi];
                const float bx1 = (bb.x - 0.5f * bb.z) * img_w;
                const float by1 = (bb.y - 0.5f * bb.w) * img_h;
                const float bx2 = (bb.x + 0.5f * bb.z) * img_w;
                const float by2 = (bb.y + 0.5f * bb.w) * img_h;
                const float o = (float)l * offc;
                const float ox1 = bx1 + o, oy1 = by1 + o, ox2 = bx2 + o, oy2 = by2 + o;
                const float ar = (ox2 - ox1) * (oy2 - oy1);
                bool alive = valid;
                for (int jj = 0; jj < kept; ++jj) {
                    float iw = fminf(sKx2[jj], ox2) - fmaxf(sKx1[jj], ox1);
                    float ih = fminf(sKy2[jj], oy2) - fmaxf(sKy1[jj], oy1);
                    iw = fmaxf(iw, 0.f); ih = fmaxf(ih, 0.f);
                    const float inter = iw * ih;
                    if (inter > IOU_THR * (sKa[jj] + ar - inter)) alive = false;
                }
                unsigned long long mask = __ballot(alive);
                while (mask != 0ULL && kept < TOPK) {
                    const int s = __ffsll((unsigned long long)mask) - 1;
                    const float px1 = __shfl(ox1, s, 64);
                    const float py1 = __shfl(oy1, s, 64);
                    const float px2 = __shfl(ox2, s, 64);
                    const float py2 = __shfl(oy2, s, 64);
                    const float pa  = __shfl(ar,  s, 64);
                    if (lane == s) {
                        sKx1[kept] = ox1; sKy1[kept] = oy1; sKx2[kept] = ox2;
                        sKy2[kept] = oy2; sKa[kept] = ar;
                        const int oi = b * TOPK + kept;
                        const float z = inv_mono((unsigned int)(k >> 17));
                        const float sc = 1.0f / (1.0f + expf(-z));
                        out[oi] = sc;
                        out[BS * TOPK + oi] = (float)l;
                        out[2 * BS * TOPK + oi * 4 + 0] = bx1;
                        out[2 * BS * TOPK + oi * 4 + 1] = by1;
                        out[2 * BS * TOPK + oi * 4 + 2] = bx2;
                        out[2 * BS * TOPK + oi * 4 + 3] = by2;
                        if (kept == 0) { sFirst[0] = sc; sFirst[1] = (float)l;
                                         sFirst[2] = bx1; sFirst[3] = by1;
                                         sFirst[4] = bx2; sFirst[5] = by2; }
                    }
                    ++kept;
                    if (alive) {
                        float iw = fminf(px2, ox2) - fmaxf(px1, ox1);
                        float ih = fminf(py2, oy2) - fmaxf(py1, oy1);
                        iw = fmaxf(iw, 0.f); ih = fmaxf(ih, 0.f);
                        const float inter = iw * ih;
                        if (inter > IOU_THR * (pa + ar - inter)) alive = false;
                    }
                    mask = __ballot(alive);
                }
            }
            if (lane == 0) sKept = kept;
        }
        __syncthreads();
    }

    // exhaustion: ref's argmax over all -inf -> index 0 -> replicate row 0
    for (int t = sKept + tid; t < TOPK; t += NT) {
        const int oi = b * TOPK + t;
        out[oi] = sFirst[0];
        out[BS * TOPK + oi] = sFirst[1];
        out[2 * BS * TOPK + oi * 4 + 0] = sFirst[2];
        out[2 * BS * TOPK + oi * 4 + 1] = sFirst[3];
        out[2 * BS * TOPK + oi * 4 + 2] = sFirst[4];
        out[2 * BS * TOPK + oi * 4 + 3] = sFirst[5];
    }
}

extern "C" void kernel_launch(void* const* d_in, const int* in_sizes, int n_in,
                              void* d_out, int out_size, void* d_ws, size_t ws_size,
                              hipStream_t stream) {
    const float* logits = (const float*)d_in[0];   // (8, 900, 91) fp32
    const float* pboxes = (const float*)d_in[1];   // (8, 900, 4) fp32
    const float* ts     = (const float*)d_in[2];   // (8, 2) fp32
    hipLaunchKernelGGL(NMSPostProcess_70463233458602_kernel,
                       dim3(BS), dim3(NT), 0, stream,
                       logits, pboxes, ts, (float*)d_out);
}

// Round 10
// 101.665 us; speedup vs baseline: 1.1244x; 1.0147x over previous
//
#include <hip/hip_runtime.h>
#include <cstdint>
#include <cstddef>

#define NQ 900
#define NC 91
#define NFLAT (NQ * NC)        // 81900
#define NF4 (NFLAT / 4)        // 20475
#define BS 8
#define PRE_TOPK 10000
#define TOPK 100
#define IOU_THR 0.7f
#define NSL 16                 // slices per batch in K1
#define K1T 256
#define NT 1024
#define NWAVES 16
#define HB 2048                // bins on z over [-4,4)
#define BINGUESS 1280          // bin_of(1.0): pool = z >= 1.0 (~13K of 81.9K)
#define SLICECAP 1280          // per-slice pool cap (exp 814, +18 sigma)
#define POOLSZ 15360           // K2 LDS pool cap (exp 13016)
#define TCAP 512               // sorted-top region capacity
#define E2CAND 256             // sorted prefix target = bitmap candidate count
#define NCAND 256
#define BBCAP 512              // crossing-bin capacity (exp ~64)
#define ELIG 0x40000000
#define LENMASK 0x3FFFFFFF

// ws layout (bytes); counts + used pool prefixes fully overwritten by K1 (poison-safe)
#define CNT_OFF 0                                  // u32 [BS][NSL]
#define POOL_OFF (BS * NSL * 4)                    // u64 [BS][NSL][SLICECAP]
#define WS_REQ ((size_t)POOL_OFF + (size_t)BS * NSL * SLICECAP * 8)

// sigmoid monotone => order on raw logit z == order on prob.
__device__ __forceinline__ unsigned int mono_u(float z) {
    unsigned int b = __float_as_uint(z);
    return b ^ ((unsigned int)((int)b >> 31) | 0x80000000u);
}
__device__ __forceinline__ float inv_mono(unsigned int u) {
    unsigned int b = (u & 0x80000000u) ? (u ^ 0x80000000u) : ~u;
    return __uint_as_float(b);
}
// 49-bit distinct key == lax.top_k order (score desc, idx asc)
__device__ __forceinline__ unsigned long long make_key(unsigned int u, int i) {
    return ((unsigned long long)u << 17) | (unsigned long long)(131071 - i);
}
__device__ __forceinline__ int bin_of(float z) {
    float t = (z + 4.0f) * 256.0f;
    t = fmaxf(t, 0.0f); t = fminf(t, 2047.0f);
    return (int)t;
}
__device__ __forceinline__ int bin_of_key(unsigned long long k) {
    return bin_of(inv_mono((unsigned int)(k >> 17)));
}

// ---------------- K1: per-slice candidate pool (z >= 1.0) ----------------
extern "C" __global__ __launch_bounds__(K1T)
void k1_pool(const float* __restrict__ logits, void* __restrict__ ws) {
    __shared__ unsigned long long pool[SLICECAP];
    __shared__ int pc;
    const int sl = blockIdx.x, b = blockIdx.y;
    const int tid = threadIdx.x, lane = tid & 63;
    const unsigned long long laneLT = (1ULL << lane) - 1ULL;
    const float* lg = logits + (size_t)b * NFLAT;
    if (tid == 0) pc = 0;
    __syncthreads();
    const int j0 = (sl * NF4) / NSL, j1 = ((sl + 1) * NF4) / NSL;
    for (int j = j0 + tid; j < j1; j += K1T) {
        const float4 v = ((const float4*)lg)[j];
        const bool c0 = v.x >= 1.0f, c1 = v.y >= 1.0f,
                   c2 = v.z >= 1.0f, c3 = v.w >= 1.0f;
        const unsigned long long m0 = __ballot(c0), m1 = __ballot(c1),
                                 m2 = __ballot(c2), m3 = __ballot(c3);
        const int p0 = __popcll(m0), p1 = __popcll(m1), p2 = __popcll(m2);
        const int n = p0 + p1 + p2 + __popcll(m3);
        int base = 0;
        if (lane == 0 && n) base = atomicAdd(&pc, n);
        base = __shfl(base, 0, 64);
        if (c0) { const int o = base + __popcll(m0 & laneLT);
                  if (o < SLICECAP) pool[o] = make_key(mono_u(v.x), 4 * j); }
        if (c1) { const int o = base + p0 + __popcll(m1 & laneLT);
                  if (o < SLICECAP) pool[o] = make_key(mono_u(v.y), 4 * j + 1); }
        if (c2) { const int o = base + p0 + p1 + __popcll(m2 & laneLT);
                  if (o < SLICECAP) pool[o] = make_key(mono_u(v.z), 4 * j + 2); }
        if (c3) { const int o = base + p0 + p1 + p2 + __popcll(m3 & laneLT);
                  if (o < SLICECAP) pool[o] = make_key(mono_u(v.w), 4 * j + 3); }
    }
    __syncthreads();
    unsigned int* cw = (unsigned int*)((char*)ws + CNT_OFF);
    if (tid == 0) cw[b * NSL + sl] = (unsigned int)pc;   // raw; K2 checks overflow
    unsigned long long* pw = (unsigned long long*)((char*)ws + POOL_OFF)
                             + ((size_t)b * NSL + sl) * SLICECAP;
    const int c = pc < SLICECAP ? pc : SLICECAP;
    for (int i = tid; i < c; i += K1T) pw[i] = pool[i];
}

// ---------------- K2: per-batch selection + bitmap NMS ----------------
extern "C" __global__ __launch_bounds__(NT)
void k2_select_nms(const float* __restrict__ logits,
                   const float* __restrict__ pboxes,
                   const float* __restrict__ tsizes,
                   float* __restrict__ out,
                   const void* __restrict__ ws,
                   const int forceBad) {
    __shared__ unsigned long long sPool[POOLSZ];      // 120 KB
    __shared__ unsigned long long sSupScan[HB / 2];   // 8 KB union: sScan / sSup
    __shared__ int sHist[HB];                         // 8 KB
    __shared__ unsigned long long sTop[TCAP];         // 4 KB sorted top prefix
    __shared__ unsigned long long sBinB[BBCAP];       // 4 KB crossing bin
    __shared__ float4 sOB[NCAND];                     // 4 KB obox
    __shared__ float sOar[NCAND];                     // 1 KB obox area
    __shared__ unsigned char sFlagB[1024];            // 1 KB per-box top-10000 flag
    __shared__ unsigned long long sKeepW[4];
    __shared__ int sKeepPos[TOPK];
    __shared__ int sOff[NSL + 1];
    __shared__ float sKx1[TOPK], sKy1[TOPK], sKx2[TOPK], sKy2[TOPK], sKa[TOPK];
    __shared__ float sFirst[6];
    __shared__ float sRedF[NWAVES];
    __shared__ int sWTot[NWAVES], sWSuf[NWAVES];
    __shared__ int sFlag, sB, sRem, sAbove, sKept, sBinBCnt, sPos, sE2, sNK, sCnt;
    __shared__ float sBmax;
    int* const sScan = (int*)sSupScan;               // lifetime: scan .. in-bin-rank
    unsigned long long* const sSup = sSupScan;       // lifetime: bitmap .. scan-NMS

    const int b = blockIdx.x;
    const int tid = threadIdx.x;
    const int wid = tid >> 6, lane = tid & 63;
    const float* lg = logits + (size_t)b * NFLAT;
    const float* bx = pboxes + (size_t)b * NQ * 4;
    const float img_h = tsizes[b * 2 + 0], img_w = tsizes[b * 2 + 1];
    const unsigned long long laneLT = (1ULL << lane) - 1ULL;

    sHist[tid] = 0; sHist[tid + NT] = 0;
    sFlagB[tid & 1023] = 0;
    if (tid == 0) { sFlag = forceBad; sBinBCnt = 0; sPos = 0; sKept = 0; sB = -1;
                    sAbove = 0; sRem = 1; sE2 = 0; sNK = 0; sCnt = 0; }
    __syncthreads();

    // ---- load pool segments ws -> contiguous LDS (+histogram during load) ----
    if (!forceBad) {
        if (tid == 0) {
            const unsigned int* cw = (const unsigned int*)((const char*)ws + CNT_OFF) + b * NSL;
            int off = 0, bad2 = 0;
            for (int sl = 0; sl < NSL; ++sl) {
                const int c = (int)cw[sl];
                if (c > SLICECAP || off + c > POOLSZ) { bad2 = 1; break; }
                sOff[sl] = off; off += c;
            }
            sOff[NSL] = off; sCnt = off;
            if (bad2) sFlag = 1;
        }
        __syncthreads();
        if (!sFlag) {
            const unsigned long long* pw =
                (const unsigned long long*)((const char*)ws + POOL_OFF)
                + (size_t)b * NSL * SLICECAP;
            for (int sl = 0; sl < NSL; ++sl) {
                const int o0 = sOff[sl], c = sOff[sl + 1] - o0;
                for (int i = tid; i < c; i += NT) {
                    const unsigned long long k = pw[(size_t)sl * SLICECAP + i];
                    sPool[o0 + i] = k;
                    atomicAdd(&sHist[bin_of_key(k)], 1);
                }
            }
        }
    }
    __syncthreads();
    const int cnt = sCnt;

    // ---- shfl hierarchical suffix scan over 2048 bins ----
    {
        const int b0 = 2 * tid, b1 = 2 * tid + 1;
        const int h0 = sHist[b0], h1 = sHist[b1];
        const int s = h0 + h1;
        int v = s;
        #pragma unroll
        for (int off = 1; off < 64; off <<= 1) {
            const int o = __shfl(v, lane + off, 64);
            if (lane + off < 64) v += o;
        }
        if (lane == 0) sWTot[wid] = v;
        __syncthreads();
        if (wid == 0) {
            int t = (lane < NWAVES) ? sWTot[lane] : 0;
            #pragma unroll
            for (int off = 1; off < NWAVES; off <<= 1) {
                const int o = __shfl(t, lane + off, 64);
                if (lane + off < NWAVES) t += o;
            }
            if (lane < NWAVES) sWSuf[lane] = t;
        }
        __syncthreads();
        const int afterWave = sWSuf[wid] - sWTot[wid];
        const int afterPairs = (v - s) + afterWave;
        const int si1 = h1 + afterPairs;
        const int si0 = h0 + si1;
        sScan[b0] = si1;          // exclusive-above = bin start
        sScan[b1] = afterPairs;
        if (si0 >= PRE_TOPK && si1 < PRE_TOPK)        { sB = b0; sAbove = si1;        sRem = PRE_TOPK - si1; }
        if (si1 >= PRE_TOPK && afterPairs < PRE_TOPK) { sB = b1; sAbove = afterPairs; sRem = PRE_TOPK - afterPairs; }
    }
    __syncthreads();
    if (tid == 0) {
        if (sB < BINGUESS) sFlag = 1;   // pool must cover the top-10000
        sE2 = sAbove < E2CAND ? sAbove : E2CAND;
    }
    __syncthreads();
    const int B = sB, above = sAbove, rem = sRem;
    int bad = sFlag;

    // ---- E2 truncation + eligible-bin marking ----
    if (!bad) {
        const int bks[2] = { 2 * tid, 2 * tid + 1 };
        #pragma unroll
        for (int q = 0; q < 2; ++q) {
            const int bk = bks[q];
            if (bk > B && sHist[bk] > 0 && sScan[bk] < E2CAND &&
                sScan[bk] + sHist[bk] > TCAP)
                atomicMin(&sE2, sScan[bk]);
        }
    }
    __syncthreads();
    if (!bad) {
        const int E2 = sE2;
        const int bks[2] = { 2 * tid, 2 * tid + 1 };
        #pragma unroll
        for (int q = 0; q < 2; ++q) {
            const int bk = bks[q];
            if (bk > B && sHist[bk] > 0 && sScan[bk] < E2) sHist[bk] |= ELIG;
        }
    }
    __syncthreads();

    // ---- SINGLE pool pass: box flags (bins>B), eligible scatter, bin-B collect ----
    if (!bad) {
        const int lim = (cnt + NT - 1) / NT * NT;
        for (int off = tid; off < lim; off += NT) {
            const bool have = off < cnt;
            const unsigned long long k = have ? sPool[off] : 0ULL;
            const int bk = have ? bin_of_key(k) : 0;
            if (have && bk > B) {
                const int i = 131071 - (int)(k & 0x1FFFFULL);
                sFlagB[i / NC] = 1;                   // definite top-10000 member
                if (sHist[bk] & ELIG) {
                    const int pos = atomicAdd(&sScan[bk], 1);
                    if (pos < TCAP) sTop[pos] = k;
                }
            }
            const bool isB = have && (bk == B);
            const unsigned long long mask = __ballot(isB);
            const int n = __popcll(mask);
            int base = 0;
            if (lane == 0 && n) base = atomicAdd(&sBinBCnt, n);
            base = __shfl(base, 0, 64);
            if (isB) {
                const int p2 = base + __popcll(mask & laneLT);
                if (p2 < BBCAP) sBinB[p2] = k;
            }
        }
    }
    __syncthreads();
    if (tid == 0 && sBinBCnt > BBCAP) sFlag = 1;
    __syncthreads();
    bad = sFlag;

    // ---- crossing bin: rank; top-rem set box flags (completes top-10000 set) ----
    if (!bad) {
        const int cntB = sBinBCnt;
        if (tid < cntB) {
            const unsigned long long kk = sBinB[tid];
            int r = 0;
            for (int q = 0; q < cntB; ++q) r += (sBinB[q] > kk) ? 1 : 0;
            if (r < rem) {
                const int i = 131071 - (int)(kk & 0x1FFFFULL);
                sFlagB[i / NC] = 1;
            }
        }
    }
    __syncthreads();

    // ---- bmax: max over flagged boxes (exactly the gathered top-10000) ----
    if (!bad) {
        float lmax = -3.4e38f;
        if (tid < NQ && sFlagB[tid]) {
            const float4 bb = ((const float4*)bx)[tid];
            const float x1 = (bb.x - 0.5f * bb.z) * img_w;
            const float y1 = (bb.y - 0.5f * bb.w) * img_h;
            const float x2 = (bb.x + 0.5f * bb.z) * img_w;
            const float y2 = (bb.y + 0.5f * bb.w) * img_h;
            lmax = fmaxf(fmaxf(x1, y1), fmaxf(x2, y2));
        }
        for (int off = 32; off >= 1; off >>= 1)
            lmax = fmaxf(lmax, __shfl_xor(lmax, off, 64));
        if (lane == 0) sRedF[wid] = lmax;
        __syncthreads();
        if (tid == 0) {
            float mm = sRedF[0];
            for (int k2 = 1; k2 < NWAVES; ++k2) mm = fmaxf(mm, sRedF[k2]);
            sBmax = mm;
        }
    }
    __syncthreads();

    // ---- in-bin rank -> exact sorted candidates sTop[0, E2) ----
    if (!bad) {
        const int E2 = sE2;
        unsigned long long k = 0ULL; int dst = -1;
        if (tid < E2) {
            k = sTop[tid];
            const int bk = bin_of_key(k);
            const int len = sHist[bk] & LENMASK;
            const int s0 = sScan[bk] - len;      // cursor - len = bin start
            int r2 = 0;
            for (int q = 0; q < len; ++q) r2 += (sTop[s0 + q] > k) ? 1 : 0;
            dst = s0 + r2;
        }
        __syncthreads();
        if (dst >= 0) sTop[dst] = k;
    }
    __syncthreads();

    // ---- candidate prep: scaled+offset boxes for first C sorted candidates ----
    const int C = (!bad) ? (sE2 < NCAND ? sE2 : NCAND) : 0;
    if (!bad && tid < C) {
        const unsigned long long k = sTop[tid];
        const int i = 131071 - (int)(k & 0x1FFFFULL);
        const int bi = i / NC, l = i - bi * NC;
        const float4 bb = ((const float4*)bx)[bi];
        const float o = (float)l * (sBmax + 1.0f);
        float4 ob;
        ob.x = (bb.x - 0.5f * bb.z) * img_w + o;
        ob.y = (bb.y - 0.5f * bb.w) * img_h + o;
        ob.z = (bb.x + 0.5f * bb.z) * img_w + o;
        ob.w = (bb.y + 0.5f * bb.w) * img_h + o;
        sOB[tid] = ob;
        sOar[tid] = (ob.z - ob.x) * (ob.w - ob.y);
    }
    __syncthreads();

    // ---- suppression bitmap via ballot (conflict-free layout) ----
    if (!bad) {
        const int w = wid & 3;
        const int r0 = (wid >> 2) << 6;
        const int cj = (w << 6) + lane;          // this lane's column candidate
        const bool cv = cj < C;
        float4 cb = make_float4(0.f, 0.f, 0.f, 0.f);
        float car = 0.f;
        if (cv) { cb = sOB[cj]; car = sOar[cj]; }
        for (int t = 0; t < 64; ++t) {
            const int i = r0 + t;
            unsigned long long bits = 0ULL;
            if (i < C) {
                const float4 rb = sOB[i];        // broadcast
                const float ra = sOar[i];        // broadcast
                bool sup = false;
                if (cv) {
                    float iw = fminf(rb.z, cb.z) - fmaxf(rb.x, cb.x);
                    float ih = fminf(rb.w, cb.w) - fmaxf(rb.y, cb.y);
                    iw = fmaxf(iw, 0.f); ih = fmaxf(ih, 0.f);
                    const float inter = iw * ih;
                    sup = inter > IOU_THR * (ra + car - inter);
                }
                bits = __ballot(sup);
            }
            if (lane == 0) sSup[(i << 2) | w] = bits;   // row i suppresses word w
        }
    }
    __syncthreads();

    // ---- bitmap scan (wave 0): per-step chain is register-only ----
    if (!bad && wid == 0) {
        unsigned long long live = 0ULL;
        if (lane < 4) {
            const int n = C - (lane << 6);
            live = (n >= 64) ? ~0ULL : ((n <= 0) ? 0ULL : ((1ULL << n) - 1ULL));
        }
        unsigned long long keepW = 0ULL;
        int kept = 0;
        const int myw = lane & 3;
        for (int ch = 0; ch < 4 && kept < TOPK; ++ch) {
            unsigned long long cur = __shfl(live, ch, 64);  // word ch, replicated
            unsigned long long acc = 0ULL;
            #pragma unroll 8
            for (int bit = 0; bit < 64; ++bit) {
                const int i = (ch << 6) | bit;
                const unsigned long long rowC = sSup[(i << 2) | ch];
                const unsigned long long rowM = sSup[(i << 2) | myw];
                if ((cur >> bit) & 1ULL) {                  // wave-uniform
                    cur &= ~rowC;
                    acc |= rowM;
                    if (lane == ch) keepW |= 1ULL << bit;
                }
            }
            if (lane < 4) live &= ~acc;
            int c = __popcll(keepW);
            for (int off = 32; off >= 1; off >>= 1) c += __shfl_xor(c, off, 64);
            kept = c;
        }
        if (lane < 4) sKeepW[lane] = keepW;
        if (lane == 0) sNK = kept;
    }
    __syncthreads();
    if (tid == 0 && !bad && sNK < TOPK) sFlag = 1;   // exhausted 256 cands -> exact path
    __syncthreads();
    bad = sFlag;

    if (!bad) {
        // keep list: first TOPK set bits in order
        if (tid < C) {
            const int w = tid >> 6;
            const unsigned long long m = sKeepW[w];
            if ((m >> (tid & 63)) & 1ULL) {
                int rank = __popcll(m & ((1ULL << (tid & 63)) - 1ULL));
                for (int ww = 0; ww < w; ++ww) rank += __popcll(sKeepW[ww]);
                if (rank < TOPK) sKeepPos[rank] = tid;
            }
        }
    }
    __syncthreads();
    if (!bad) {
        // parallel outputs (incl. all sigmoids)
        if (tid < TOPK) {
            const int p = sKeepPos[tid];
            const unsigned long long k = sTop[p];
            const int i = 131071 - (int)(k & 0x1FFFFULL);
            const int bi = i / NC, l = i - bi * NC;
            const float4 bb = ((const float4*)bx)[bi];
            const float bx1 = (bb.x - 0.5f * bb.z) * img_w;
            const float by1 = (bb.y - 0.5f * bb.w) * img_h;
            const float bx2 = (bb.x + 0.5f * bb.z) * img_w;
            const float by2 = (bb.y + 0.5f * bb.w) * img_h;
            const float z = inv_mono((unsigned int)(k >> 17));
            const int oi = b * TOPK + tid;
            out[oi] = 1.0f / (1.0f + expf(-z));
            out[BS * TOPK + oi] = (float)l;
            out[2 * BS * TOPK + oi * 4 + 0] = bx1;
            out[2 * BS * TOPK + oi * 4 + 1] = by1;
            out[2 * BS * TOPK + oi * 4 + 2] = bx2;
            out[2 * BS * TOPK + oi * 4 + 3] = by2;
        }
        if (tid == 0) sKept = TOPK;
    }
    __syncthreads();

    if (bad) {
        // ======== exact fallback (never taken for sane inputs) ========
        unsigned long long lo = 0, hi = (1ULL << 49) - 1;
        while (lo < hi) {
            const unsigned long long mid = lo + ((hi - lo + 1) >> 1);
            int c = 0;
            for (int j = tid; j < NF4; j += NT) {
                const float4 v = ((const float4*)lg)[j];
                const float zv[4] = { v.x, v.y, v.z, v.w };
                #pragma unroll
                for (int q = 0; q < 4; ++q)
                    c += (make_key(mono_u(zv[q]), 4 * j + q) >= mid) ? 1 : 0;
            }
            for (int off = 32; off >= 1; off >>= 1) c += __shfl_xor(c, off, 64);
            if (lane == 0) sWTot[wid] = c;
            __syncthreads();
            if (tid == 0) {
                int a = 0;
                for (int w = 0; w < NWAVES; ++w) a += sWTot[w];
                sPos = a;
            }
            __syncthreads();
            if (sPos >= PRE_TOPK) lo = mid; else hi = mid - 1;
            __syncthreads();
        }
        if (tid == 0) sPos = 0;
        __syncthreads();
        for (int j = tid; j < NF4; j += NT) {
            const float4 v = ((const float4*)lg)[j];
            const float zv[4] = { v.x, v.y, v.z, v.w };
            #pragma unroll
            for (int q = 0; q < 4; ++q) {
                const unsigned long long k = make_key(mono_u(zv[q]), 4 * j + q);
                const bool cand = k >= lo;        // exactly 10000 (keys distinct)
                const unsigned long long mask = __ballot(cand);
                int pos = 0;
                if (lane == 0 && mask) pos = atomicAdd(&sPos, __popcll(mask));
                pos = __shfl(pos, 0, 64);
                if (cand) sPool[pos + __popcll(mask & laneLT)] = k;
            }
        }
        __syncthreads();
        {   // full rank sort of 10000 (slow, correct)
            unsigned long long stash[10]; int spp[10]; int ns = 0;
            for (int p = tid; p < PRE_TOPK; p += NT) {
                const unsigned long long k = sPool[p];
                int r = 0;
                for (int q = 0; q < PRE_TOPK; ++q) r += (sPool[q] > k) ? 1 : 0;
                if (ns < 10) { stash[ns] = k; spp[ns] = r; ++ns; }
            }
            __syncthreads();
            for (int q = 0; q < ns; ++q) sPool[spp[q]] = stash[q];
        }
        __syncthreads();
        float lmax = -3.4e38f;
        for (int p = tid; p < PRE_TOPK; p += NT) {
            const int i = 131071 - (int)(sPool[p] & 0x1FFFFULL);
            const int bi = i / NC;
            const float4 bb = ((const float4*)bx)[bi];
            const float x1 = (bb.x - 0.5f * bb.z) * img_w;
            const float y1 = (bb.y - 0.5f * bb.w) * img_h;
            const float x2 = (bb.x + 0.5f * bb.z) * img_w;
            const float y2 = (bb.y + 0.5f * bb.w) * img_h;
            lmax = fmaxf(lmax, fmaxf(fmaxf(x1, y1), fmaxf(x2, y2)));
        }
        for (int off = 32; off >= 1; off >>= 1)
            lmax = fmaxf(lmax, __shfl_xor(lmax, off, 64));
        if (lane == 0) sRedF[wid] = lmax;
        __syncthreads();
        if (tid == 0) {
            float mm = sRedF[0];
            for (int k2 = 1; k2 < NWAVES; ++k2) mm = fmaxf(mm, sRedF[k2]);
            sBmax = mm;
        }
        __syncthreads();
        const float offc = sBmax + 1.0f;
        if (wid == 0) {
            int kept = 0;
            for (int base = 0; base < PRE_TOPK && kept < TOPK; base += 64) {
                const int c = base + lane;
                const bool valid = c < PRE_TOPK;
                const unsigned long long k = valid ? sPool[c] : 0ULL;
                const int i = valid ? (131071 - (int)(k & 0x1FFFFULL)) : 0;
                const int bi = i / NC, l = i - bi * NC;
                const float4 bb = ((const float4*)bx)[bi];
                const float bx1 = (bb.x - 0.5f * bb.z) * img_w;
                const float by1 = (bb.y - 0.5f * bb.w) * img_h;
                const float bx2 = (bb.x + 0.5f * bb.z) * img_w;
                const float by2 = (bb.y + 0.5f * bb.w) * img_h;
                const float o = (float)l * offc;
                const float ox1 = bx1 + o, oy1 = by1 + o, ox2 = bx2 + o, oy2 = by2 + o;
                const float ar = (ox2 - ox1) * (oy2 - oy1);
                bool alive = valid;
                for (int jj = 0; jj < kept; ++jj) {
                    float iw = fminf(sKx2[jj], ox2) - fmaxf(sKx1[jj], ox1);
                    float ih = fminf(sKy2[jj], oy2) - fmaxf(sKy1[jj], oy1);
                    iw = fmaxf(iw, 0.f); ih = fmaxf(ih, 0.f);
                    const float inter = iw * ih;
                    if (inter > IOU_THR * (sKa[jj] + ar - inter)) alive = false;
                }
                unsigned long long mask = __ballot(alive);
                while (mask != 0ULL && kept < TOPK) {
                    const int s = __ffsll((unsigned long long)mask) - 1;
                    const float px1 = __shfl(ox1, s, 64);
                    const float py1 = __shfl(oy1, s, 64);
                    const float px2 = __shfl(ox2, s, 64);
                    const float py2 = __shfl(oy2, s, 64);
                    const float pa  = __shfl(ar,  s, 64);
                    if (lane == s) {
                        sKx1[kept] = ox1; sKy1[kept] = oy1; sKx2[kept] = ox2;
                        sKy2[kept] = oy2; sKa[kept] = ar;
                        const int oi = b * TOPK + kept;
                        const float z = inv_mono((unsigned int)(k >> 17));
                        const float sc = 1.0f / (1.0f + expf(-z));
                        out[oi] = sc;
                        out[BS * TOPK + oi] = (float)l;
                        out[2 * BS * TOPK + oi * 4 + 0] = bx1;
                        out[2 * BS * TOPK + oi * 4 + 1] = by1;
                        out[2 * BS * TOPK + oi * 4 + 2] = bx2;
                        out[2 * BS * TOPK + oi * 4 + 3] = by2;
                        if (kept == 0) { sFirst[0] = sc; sFirst[1] = (float)l;
                                         sFirst[2] = bx1; sFirst[3] = by1;
                                         sFirst[4] = bx2; sFirst[5] = by2; }
                    }
                    ++kept;
                    if (alive) {
                        float iw = fminf(px2, ox2) - fmaxf(px1, ox1);
                        float ih = fminf(py2, oy2) - fmaxf(py1, oy1);
                        iw = fmaxf(iw, 0.f); ih = fmaxf(ih, 0.f);
                        const float inter = iw * ih;
                        if (inter > IOU_THR * (pa + ar - inter)) alive = false;
                    }
                    mask = __ballot(alive);
                }
            }
            if (lane == 0) sKept = kept;
        }
        __syncthreads();
    }

    // exhaustion: ref's argmax over all -inf -> index 0 -> replicate row 0
    for (int t = sKept + tid; t < TOPK; t += NT) {
        const int oi = b * TOPK + t;
        out[oi] = sFirst[0];
        out[BS * TOPK + oi] = sFirst[1];
        out[2 * BS * TOPK + oi * 4 + 0] = sFirst[2];
        out[2 * BS * TOPK + oi * 4 + 1] = sFirst[3];
        out[2 * BS * TOPK + oi * 4 + 2] = sFirst[4];
        out[2 * BS * TOPK + oi * 4 + 3] = sFirst[5];
    }
}

extern "C" void kernel_launch(void* const* d_in, const int* in_sizes, int n_in,
                              void* d_out, int out_size, void* d_ws, size_t ws_size,
                              hipStream_t stream) {
    const float* logits = (const float*)d_in[0];   // (8, 900, 91) fp32
    const float* pboxes = (const float*)d_in[1];   // (8, 900, 4) fp32
    const float* ts     = (const float*)d_in[2];   // (8, 2) fp32
    if (ws_size >= WS_REQ) {
        hipLaunchKernelGGL(k1_pool, dim3(NSL, BS), dim3(K1T), 0, stream,
                           logits, d_ws);
        hipLaunchKernelGGL(k2_select_nms, dim3(BS), dim3(NT), 0, stream,
                           logits, pboxes, ts, (float*)d_out, d_ws, 0);
    } else {
        // no workspace: exact in-kernel fallback path (slow, correct)
        hipLaunchKernelGGL(k2_select_nms, dim3(BS), dim3(NT), 0, stream,
                           logits, pboxes, ts, (float*)d_out, d_ws, 1);
    }
}

// Round 11
// 100.230 us; speedup vs baseline: 1.1405x; 1.0143x over previous
//
#include <hip/hip_runtime.h>
#include <cstdint>
#include <cstddef>

#define NQ 900
#define NC 91
#define NFLAT (NQ * NC)        // 81900
#define NF4 (NFLAT / 4)        // 20475
#define BS 8
#define PRE_TOPK 10000
#define TOPK 100
#define IOU_THR 0.7f
#define NSL 16                 // K1 slices per batch
#define K1T 256
#define NT 1024
#define NWAVES 16
#define HB 2048                // bins on z over [-4,4)
#define BINGUESS 1311          // pool = bin >= 1311 (z >~ 1.121, E=10737, sig=97)
#define K1CAP 1024             // K1 per-block LDS pool cap (exp 671, +14.6 sigma)
#define POOLCAP 12288          // per-batch pool cap (E +16 sigma)
#define TCAP 512               // sorted-top region capacity
#define E2CAND 256             // sorted prefix target = bitmap candidate count
#define NCAND 256
#define BBCAP 512              // crossing-bin capacity (exp ~68)
#define ELIG 0x40000000
#define LENMASK 0x3FFFFFFF

// ws layout (bytes): cursors zeroed via hipMemsetAsync each launch (poison-safe)
#define CUR_OFF 0                                  // u32 [BS] atomic cursors
#define POOL_OFF 256                               // u64 [BS][POOLCAP]
#define WS_REQ ((size_t)POOL_OFF + (size_t)BS * POOLCAP * 8)

// sigmoid monotone => order on raw logit z == order on prob.
__device__ __forceinline__ unsigned int mono_u(float z) {
    unsigned int b = __float_as_uint(z);
    return b ^ ((unsigned int)((int)b >> 31) | 0x80000000u);
}
__device__ __forceinline__ float inv_mono(unsigned int u) {
    unsigned int b = (u & 0x80000000u) ? (u ^ 0x80000000u) : ~u;
    return __uint_as_float(b);
}
// 49-bit distinct key == lax.top_k order (score desc, idx asc)
__device__ __forceinline__ unsigned long long make_key(unsigned int u, int i) {
    return ((unsigned long long)u << 17) | (unsigned long long)(131071 - i);
}
__device__ __forceinline__ int bin_of(float z) {
    float t = (z + 4.0f) * 256.0f;
    t = fmaxf(t, 0.0f); t = fminf(t, 2047.0f);
    return (int)t;
}
__device__ __forceinline__ int bin_of_key(unsigned long long k) {
    return bin_of(inv_mono((unsigned int)(k >> 17)));
}

// ---------------- K1: candidate pool -> compact global (atomic cursor) ----------------
extern "C" __global__ __launch_bounds__(K1T)
void k1_pool(const float* __restrict__ logits, void* __restrict__ ws) {
    __shared__ unsigned long long pool[K1CAP];
    __shared__ int pc, gbase;
    const int sl = blockIdx.x, b = blockIdx.y;
    const int tid = threadIdx.x, lane = tid & 63;
    const unsigned long long laneLT = (1ULL << lane) - 1ULL;
    const float* lg = logits + (size_t)b * NFLAT;
    if (tid == 0) pc = 0;
    __syncthreads();
    const int j0 = (sl * NF4) / NSL, j1 = ((sl + 1) * NF4) / NSL;
    for (int j = j0 + tid; j < j1; j += K1T) {
        const float4 v = ((const float4*)lg)[j];
        const bool c0 = bin_of(v.x) >= BINGUESS, c1 = bin_of(v.y) >= BINGUESS,
                   c2 = bin_of(v.z) >= BINGUESS, c3 = bin_of(v.w) >= BINGUESS;
        const unsigned long long m0 = __ballot(c0), m1 = __ballot(c1),
                                 m2 = __ballot(c2), m3 = __ballot(c3);
        const int p0 = __popcll(m0), p1 = __popcll(m1), p2 = __popcll(m2);
        const int n = p0 + p1 + p2 + __popcll(m3);
        int base = 0;
        if (lane == 0 && n) base = atomicAdd(&pc, n);
        base = __shfl(base, 0, 64);
        if (c0) { const int o = base + __popcll(m0 & laneLT);
                  if (o < K1CAP) pool[o] = make_key(mono_u(v.x), 4 * j); }
        if (c1) { const int o = base + p0 + __popcll(m1 & laneLT);
                  if (o < K1CAP) pool[o] = make_key(mono_u(v.y), 4 * j + 1); }
        if (c2) { const int o = base + p0 + p1 + __popcll(m2 & laneLT);
                  if (o < K1CAP) pool[o] = make_key(mono_u(v.z), 4 * j + 2); }
        if (c3) { const int o = base + p0 + p1 + p2 + __popcll(m3 & laneLT);
                  if (o < K1CAP) pool[o] = make_key(mono_u(v.w), 4 * j + 3); }
    }
    __syncthreads();
    const int n = pc < K1CAP ? pc : K1CAP;
    if (tid == 0) {
        unsigned int* cur = (unsigned int*)((char*)ws + CUR_OFF);
        // overflow of LDS cap poisons the cursor -> K2 takes exact fallback
        gbase = (int)atomicAdd(&cur[b], (unsigned int)(pc < K1CAP ? pc : POOLCAP + 1));
    }
    __syncthreads();
    const int base = gbase;
    unsigned long long* pw = (unsigned long long*)((char*)ws + POOL_OFF)
                             + (size_t)b * POOLCAP;
    for (int i = tid; i < n; i += K1T)
        if (base + i < POOLCAP) pw[base + i] = pool[i];
}

// ---------------- K2: per-batch selection + bitmap NMS ----------------
extern "C" __global__ __launch_bounds__(NT)
void k2_select_nms(const float* __restrict__ logits,
                   const float* __restrict__ pboxes,
                   const float* __restrict__ tsizes,
                   float* __restrict__ out,
                   const void* __restrict__ ws,
                   const int forceBad) {
    __shared__ unsigned long long sPool[POOLCAP];     // 96 KB
    __shared__ unsigned long long sSupScan[HB / 2];   // 8 KB union: sScan / sSup
    __shared__ int sHist[HB];                         // 8 KB
    __shared__ float4 sBox[NQ];                       // 14.4 KB scaled xyxy boxes
    __shared__ unsigned long long sTop[TCAP];         // 4 KB sorted top prefix
    __shared__ unsigned long long sBinB[BBCAP];       // 4 KB crossing bin
    __shared__ float4 sOB[NCAND];                     // 4 KB offset obox
    __shared__ float sOar[NCAND];                     // 1 KB obox area
    __shared__ unsigned char sFlagB[1024];            // 1 KB per-box top-10000 flag
    __shared__ unsigned long long sKeepW[4];
    __shared__ int sKeepPos[TOPK];
    __shared__ float sKx1[TOPK], sKy1[TOPK], sKx2[TOPK], sKy2[TOPK], sKa[TOPK];
    __shared__ float sFirst[6];
    __shared__ float sRedF[NWAVES];
    __shared__ int sWTot[NWAVES], sWSuf[NWAVES];
    __shared__ int sFlag, sB, sRem, sAbove, sKept, sBinBCnt, sPos, sE2, sNK, sCnt;
    __shared__ float sBmax;
    int* const sScan = (int*)sSupScan;               // lifetime: scan .. in-bin-rank
    unsigned long long* const sSup = sSupScan;       // lifetime: bitmap .. scan-NMS

    const int b = blockIdx.x;
    const int tid = threadIdx.x;
    const int wid = tid >> 6, lane = tid & 63;
    const float* lg = logits + (size_t)b * NFLAT;
    const float* bx = pboxes + (size_t)b * NQ * 4;
    const float img_h = tsizes[b * 2 + 0], img_w = tsizes[b * 2 + 1];
    const unsigned long long laneLT = (1ULL << lane) - 1ULL;

    sHist[tid] = 0; sHist[tid + NT] = 0;
    sFlagB[tid & 1023] = 0;
    if (tid == 0) { sFlag = forceBad; sBinBCnt = 0; sPos = 0; sKept = 0; sB = -1;
                    sAbove = 0; sRem = 1; sE2 = 0; sNK = 0; sCnt = 0; }
    // ---- stage all 900 scaled boxes into LDS (overlaps cursor-read latency) ----
    if (tid < NQ) {
        const float4 bb = ((const float4*)bx)[tid];
        float4 sb;
        sb.x = (bb.x - 0.5f * bb.z) * img_w;
        sb.y = (bb.y - 0.5f * bb.w) * img_h;
        sb.z = (bb.x + 0.5f * bb.z) * img_w;
        sb.w = (bb.y + 0.5f * bb.w) * img_h;
        sBox[tid] = sb;
    }
    if (!forceBad && tid == 0) {
        const unsigned int cur = ((const unsigned int*)((const char*)ws + CUR_OFF))[b];
        if (cur > POOLCAP) sFlag = 1;
        sCnt = cur > POOLCAP ? 0 : (int)cur;
    }
    __syncthreads();
    const int cnt = sCnt;

    // ---- coalesced parallel pool load (+histogram during load) ----
    if (!sFlag) {
        const unsigned long long* pw =
            (const unsigned long long*)((const char*)ws + POOL_OFF) + (size_t)b * POOLCAP;
        for (int p = tid; p < cnt; p += NT) {
            const unsigned long long k = pw[p];
            sPool[p] = k;
            atomicAdd(&sHist[bin_of_key(k)], 1);
        }
    }
    __syncthreads();

    // ---- shfl hierarchical suffix scan over 2048 bins ----
    {
        const int b0 = 2 * tid, b1 = 2 * tid + 1;
        const int h0 = sHist[b0], h1 = sHist[b1];
        const int s = h0 + h1;
        int v = s;
        #pragma unroll
        for (int off = 1; off < 64; off <<= 1) {
            const int o = __shfl(v, lane + off, 64);
            if (lane + off < 64) v += o;
        }
        if (lane == 0) sWTot[wid] = v;
        __syncthreads();
        if (wid == 0) {
            int t = (lane < NWAVES) ? sWTot[lane] : 0;
            #pragma unroll
            for (int off = 1; off < NWAVES; off <<= 1) {
                const int o = __shfl(t, lane + off, 64);
                if (lane + off < NWAVES) t += o;
            }
            if (lane < NWAVES) sWSuf[lane] = t;
        }
        __syncthreads();
        const int afterWave = sWSuf[wid] - sWTot[wid];
        const int afterPairs = (v - s) + afterWave;
        const int si1 = h1 + afterPairs;
        const int si0 = h0 + si1;
        sScan[b0] = si1;          // exclusive-above = bin start
        sScan[b1] = afterPairs;
        if (si0 >= PRE_TOPK && si1 < PRE_TOPK)        { sB = b0; sAbove = si1;        sRem = PRE_TOPK - si1; }
        if (si1 >= PRE_TOPK && afterPairs < PRE_TOPK) { sB = b1; sAbove = afterPairs; sRem = PRE_TOPK - afterPairs; }
    }
    __syncthreads();
    if (tid == 0) {
        if (sB < BINGUESS) sFlag = 1;   // pool must cover the top-10000
        sE2 = sAbove < E2CAND ? sAbove : E2CAND;
    }
    __syncthreads();
    const int B = sB, above = sAbove, rem = sRem;
    int bad = sFlag;

    // ---- E2 truncation + eligible-bin marking ----
    if (!bad) {
        const int bks[2] = { 2 * tid, 2 * tid + 1 };
        #pragma unroll
        for (int q = 0; q < 2; ++q) {
            const int bk = bks[q];
            if (bk > B && sHist[bk] > 0 && sScan[bk] < E2CAND &&
                sScan[bk] + sHist[bk] > TCAP)
                atomicMin(&sE2, sScan[bk]);
        }
    }
    __syncthreads();
    if (!bad) {
        const int E2 = sE2;
        const int bks[2] = { 2 * tid, 2 * tid + 1 };
        #pragma unroll
        for (int q = 0; q < 2; ++q) {
            const int bk = bks[q];
            if (bk > B && sHist[bk] > 0 && sScan[bk] < E2) sHist[bk] |= ELIG;
        }
    }
    __syncthreads();

    // ---- SINGLE pool pass: box flags (bins>B), eligible scatter, bin-B collect ----
    if (!bad) {
        const int lim = (cnt + NT - 1) / NT * NT;
        for (int off = tid; off < lim; off += NT) {
            const bool have = off < cnt;
            const unsigned long long k = have ? sPool[off] : 0ULL;
            const int bk = have ? bin_of_key(k) : 0;
            if (have && bk > B) {
                const int i = 131071 - (int)(k & 0x1FFFFULL);
                sFlagB[i / NC] = 1;                   // definite top-10000 member
                if (sHist[bk] & ELIG) {
                    const int pos = atomicAdd(&sScan[bk], 1);
                    if (pos < TCAP) sTop[pos] = k;
                }
            }
            const bool isB = have && (bk == B);
            const unsigned long long mask = __ballot(isB);
            const int n = __popcll(mask);
            int base = 0;
            if (lane == 0 && n) base = atomicAdd(&sBinBCnt, n);
            base = __shfl(base, 0, 64);
            if (isB) {
                const int p2 = base + __popcll(mask & laneLT);
                if (p2 < BBCAP) sBinB[p2] = k;
            }
        }
    }
    __syncthreads();
    if (tid == 0 && sBinBCnt > BBCAP) sFlag = 1;
    __syncthreads();
    bad = sFlag;

    // ---- crossing bin: rank; top-rem set box flags (completes top-10000 set) ----
    if (!bad) {
        const int cntB = sBinBCnt;
        if (tid < cntB) {
            const unsigned long long kk = sBinB[tid];
            int r = 0;
            for (int q = 0; q < cntB; ++q) r += (sBinB[q] > kk) ? 1 : 0;
            if (r < rem) {
                const int i = 131071 - (int)(kk & 0x1FFFFULL);
                sFlagB[i / NC] = 1;
            }
        }
    }
    __syncthreads();

    // ---- bmax: max over flagged boxes, all from LDS ----
    if (!bad) {
        float lmax = -3.4e38f;
        if (tid < NQ && sFlagB[tid]) {
            const float4 sb = sBox[tid];
            lmax = fmaxf(fmaxf(sb.x, sb.y), fmaxf(sb.z, sb.w));
        }
        for (int off = 32; off >= 1; off >>= 1)
            lmax = fmaxf(lmax, __shfl_xor(lmax, off, 64));
        if (lane == 0) sRedF[wid] = lmax;
        __syncthreads();
        if (tid == 0) {
            float mm = sRedF[0];
            for (int k2 = 1; k2 < NWAVES; ++k2) mm = fmaxf(mm, sRedF[k2]);
            sBmax = mm;
        }
    }
    __syncthreads();

    // ---- in-bin rank -> exact sorted candidates sTop[0, E2) ----
    if (!bad) {
        const int E2 = sE2;
        unsigned long long k = 0ULL; int dst = -1;
        if (tid < E2) {
            k = sTop[tid];
            const int bk = bin_of_key(k);
            const int len = sHist[bk] & LENMASK;
            const int s0 = sScan[bk] - len;      // cursor - len = bin start
            int r2 = 0;
            for (int q = 0; q < len; ++q) r2 += (sTop[s0 + q] > k) ? 1 : 0;
            dst = s0 + r2;
        }
        __syncthreads();
        if (dst >= 0) sTop[dst] = k;
    }
    __syncthreads();

    // ---- candidate prep: offset boxes for first C sorted candidates (LDS) ----
    const int C = (!bad) ? (sE2 < NCAND ? sE2 : NCAND) : 0;
    if (!bad && tid < C) {
        const unsigned long long k = sTop[tid];
        const int i = 131071 - (int)(k & 0x1FFFFULL);
        const int bi = i / NC, l = i - bi * NC;
        const float4 sb = sBox[bi];
        const float o = (float)l * (sBmax + 1.0f);
        float4 ob;
        ob.x = sb.x + o; ob.y = sb.y + o; ob.z = sb.z + o; ob.w = sb.w + o;
        sOB[tid] = ob;
        sOar[tid] = (ob.z - ob.x) * (ob.w - ob.y);
    }
    __syncthreads();

    // ---- suppression bitmap via ballot (conflict-free layout) ----
    if (!bad) {
        const int w = wid & 3;
        const int r0 = (wid >> 2) << 6;
        const int cj = (w << 6) + lane;          // this lane's column candidate
        const bool cv = cj < C;
        float4 cb = make_float4(0.f, 0.f, 0.f, 0.f);
        float car = 0.f;
        if (cv) { cb = sOB[cj]; car = sOar[cj]; }
        for (int t = 0; t < 64; ++t) {
            const int i = r0 + t;
            unsigned long long bits = 0ULL;
            if (i < C) {
                const float4 rb = sOB[i];        // broadcast
                const float ra = sOar[i];        // broadcast
                bool sup = false;
                if (cv) {
                    float iw = fminf(rb.z, cb.z) - fmaxf(rb.x, cb.x);
                    float ih = fminf(rb.w, cb.w) - fmaxf(rb.y, cb.y);
                    iw = fmaxf(iw, 0.f); ih = fmaxf(ih, 0.f);
                    const float inter = iw * ih;
                    sup = inter > IOU_THR * (ra + car - inter);
                }
                bits = __ballot(sup);
            }
            if (lane == 0) sSup[(i << 2) | w] = bits;   // row i suppresses word w
        }
    }
    __syncthreads();

    // ---- bitmap scan (wave 0): per-step chain is register-only ----
    if (!bad && wid == 0) {
        unsigned long long live = 0ULL;
        if (lane < 4) {
            const int n = C - (lane << 6);
            live = (n >= 64) ? ~0ULL : ((n <= 0) ? 0ULL : ((1ULL << n) - 1ULL));
        }
        unsigned long long keepW = 0ULL;
        int kept = 0;
        const int myw = lane & 3;
        for (int ch = 0; ch < 4 && kept < TOPK; ++ch) {
            unsigned long long cur = __shfl(live, ch, 64);  // word ch, replicated
            unsigned long long acc = 0ULL;
            #pragma unroll 8
            for (int bit = 0; bit < 64; ++bit) {
                const int i = (ch << 6) | bit;
                const unsigned long long rowC = sSup[(i << 2) | ch];
                const unsigned long long rowM = sSup[(i << 2) | myw];
                if ((cur >> bit) & 1ULL) {                  // wave-uniform
                    cur &= ~rowC;
                    acc |= rowM;
                    if (lane == ch) keepW |= 1ULL << bit;
                }
            }
            if (lane < 4) live &= ~acc;
            int c = __popcll(keepW);
            for (int off = 32; off >= 1; off >>= 1) c += __shfl_xor(c, off, 64);
            kept = c;
        }
        if (lane < 4) sKeepW[lane] = keepW;
        if (lane == 0) sNK = kept;
    }
    __syncthreads();
    if (tid == 0 && !bad && sNK < TOPK) sFlag = 1;   // exhausted 256 cands -> exact path
    __syncthreads();
    bad = sFlag;

    if (!bad) {
        // keep list: first TOPK set bits in order
        if (tid < C) {
            const int w = tid >> 6;
            const unsigned long long m = sKeepW[w];
            if ((m >> (tid & 63)) & 1ULL) {
                int rank = __popcll(m & ((1ULL << (tid & 63)) - 1ULL));
                for (int ww = 0; ww < w; ++ww) rank += __popcll(sKeepW[ww]);
                if (rank < TOPK) sKeepPos[rank] = tid;
            }
        }
    }
    __syncthreads();
    if (!bad) {
        // parallel outputs (incl. all sigmoids)
        if (tid < TOPK) {
            const int p = sKeepPos[tid];
            const unsigned long long k = sTop[p];
            const int i = 131071 - (int)(k & 0x1FFFFULL);
            const int bi = i / NC, l = i - bi * NC;
            const float4 sb = sBox[bi];
            const float z = inv_mono((unsigned int)(k >> 17));
            const int oi = b * TOPK + tid;
            out[oi] = 1.0f / (1.0f + expf(-z));
            out[BS * TOPK + oi] = (float)l;
            out[2 * BS * TOPK + oi * 4 + 0] = sb.x;
            out[2 * BS * TOPK + oi * 4 + 1] = sb.y;
            out[2 * BS * TOPK + oi * 4 + 2] = sb.z;
            out[2 * BS * TOPK + oi * 4 + 3] = sb.w;
        }
        if (tid == 0) sKept = TOPK;
    }
    __syncthreads();

    if (bad) {
        // ======== exact fallback (never taken for sane inputs) ========
        unsigned long long lo = 0, hi = (1ULL << 49) - 1;
        while (lo < hi) {
            const unsigned long long mid = lo + ((hi - lo + 1) >> 1);
            int c = 0;
            for (int j = tid; j < NF4; j += NT) {
                const float4 v = ((const float4*)lg)[j];
                const float zv[4] = { v.x, v.y, v.z, v.w };
                #pragma unroll
                for (int q = 0; q < 4; ++q)
                    c += (make_key(mono_u(zv[q]), 4 * j + q) >= mid) ? 1 : 0;
            }
            for (int off = 32; off >= 1; off >>= 1) c += __shfl_xor(c, off, 64);
            if (lane == 0) sWTot[wid] = c;
            __syncthreads();
            if (tid == 0) {
                int a = 0;
                for (int w = 0; w < NWAVES; ++w) a += sWTot[w];
                sPos = a;
            }
            __syncthreads();
            if (sPos >= PRE_TOPK) lo = mid; else hi = mid - 1;
            __syncthreads();
        }
        if (tid == 0) sPos = 0;
        __syncthreads();
        for (int j = tid; j < NF4; j += NT) {
            const float4 v = ((const float4*)lg)[j];
            const float zv[4] = { v.x, v.y, v.z, v.w };
            #pragma unroll
            for (int q = 0; q < 4; ++q) {
                const unsigned long long k = make_key(mono_u(zv[q]), 4 * j + q);
                const bool cand = k >= lo;        // exactly 10000 (keys distinct)
                const unsigned long long mask = __ballot(cand);
                int pos = 0;
                if (lane == 0 && mask) pos = atomicAdd(&sPos, __popcll(mask));
                pos = __shfl(pos, 0, 64);
                if (cand) sPool[pos + __popcll(mask & laneLT)] = k;
            }
        }
        __syncthreads();
        {   // full rank sort of 10000 (slow, correct)
            unsigned long long stash[10]; int spp[10]; int ns = 0;
            for (int p = tid; p < PRE_TOPK; p += NT) {
                const unsigned long long k = sPool[p];
                int r = 0;
                for (int q = 0; q < PRE_TOPK; ++q) r += (sPool[q] > k) ? 1 : 0;
                if (ns < 10) { stash[ns] = k; spp[ns] = r; ++ns; }
            }
            __syncthreads();
            for (int q = 0; q < ns; ++q) sPool[spp[q]] = stash[q];
        }
        __syncthreads();
        float lmax = -3.4e38f;
        for (int p = tid; p < PRE_TOPK; p += NT) {
            const int i = 131071 - (int)(sPool[p] & 0x1FFFFULL);
            const float4 sb = sBox[i / NC];
            lmax = fmaxf(lmax, fmaxf(fmaxf(sb.x, sb.y), fmaxf(sb.z, sb.w)));
        }
        for (int off = 32; off >= 1; off >>= 1)
            lmax = fmaxf(lmax, __shfl_xor(lmax, off, 64));
        if (lane == 0) sRedF[wid] = lmax;
        __syncthreads();
        if (tid == 0) {
            float mm = sRedF[0];
            for (int k2 = 1; k2 < NWAVES; ++k2) mm = fmaxf(mm, sRedF[k2]);
            sBmax = mm;
        }
        __syncthreads();
        const float offc = sBmax + 1.0f;
        if (wid == 0) {
            int kept = 0;
            for (int base = 0; base < PRE_TOPK && kept < TOPK; base += 64) {
                const int c = base + lane;
                const bool valid = c < PRE_TOPK;
                const unsigned long long k = valid ? sPool[c] : 0ULL;
                const int i = valid ? (131071 - (int)(k & 0x1FFFFULL)) : 0;
                const int bi = i / NC, l = i - bi * NC;
                const float4 sb = sBox[bi];
                const float o = (float)l * offc;
                const float ox1 = sb.x + o, oy1 = sb.y + o, ox2 = sb.z + o, oy2 = sb.w + o;
                const float ar = (ox2 - ox1) * (oy2 - oy1);
                bool alive = valid;
                for (int jj = 0; jj < kept; ++jj) {
                    float iw = fminf(sKx2[jj], ox2) - fmaxf(sKx1[jj], ox1);
                    float ih = fminf(sKy2[jj], oy2) - fmaxf(sKy1[jj], oy1);
                    iw = fmaxf(iw, 0.f); ih = fmaxf(ih, 0.f);
                    const float inter = iw * ih;
                    if (inter > IOU_THR * (sKa[jj] + ar - inter)) alive = false;
                }
                unsigned long long mask = __ballot(alive);
                while (mask != 0ULL && kept < TOPK) {
                    const int s = __ffsll((unsigned long long)mask) - 1;
                    const float px1 = __shfl(ox1, s, 64);
                    const float py1 = __shfl(oy1, s, 64);
                    const float px2 = __shfl(ox2, s, 64);
                    const float py2 = __shfl(oy2, s, 64);
                    const float pa  = __shfl(ar,  s, 64);
                    if (lane == s) {
                        sKx1[kept] = ox1; sKy1[kept] = oy1; sKx2[kept] = ox2;
                        sKy2[kept] = oy2; sKa[kept] = ar;
                        const int oi = b * TOPK + kept;
                        const float z = inv_mono((unsigned int)(k >> 17));
                        const float sc = 1.0f / (1.0f + expf(-z));
                        out[oi] = sc;
                        out[BS * TOPK + oi] = (float)l;
                        out[2 * BS * TOPK + oi * 4 + 0] = sb.x;
                        out[2 * BS * TOPK + oi * 4 + 1] = sb.y;
                        out[2 * BS * TOPK + oi * 4 + 2] = sb.z;
                        out[2 * BS * TOPK + oi * 4 + 3] = sb.w;
                        if (kept == 0) { sFirst[0] = sc; sFirst[1] = (float)l;
                                         sFirst[2] = sb.x; sFirst[3] = sb.y;
                                         sFirst[4] = sb.z; sFirst[5] = sb.w; }
                    }
                    ++kept;
                    if (alive) {
                        float iw = fminf(px2, ox2) - fmaxf(px1, ox1);
                        float ih = fminf(py2, oy2) - fmaxf(py1, oy1);
                        iw = fmaxf(iw, 0.f); ih = fmaxf(ih, 0.f);
                        const float inter = iw * ih;
                        if (inter > IOU_THR * (pa + ar - inter)) alive = false;
                    }
                    mask = __ballot(alive);
                }
            }
            if (lane == 0) sKept = kept;
        }
        __syncthreads();
    }

    // exhaustion: ref's argmax over all -inf -> index 0 -> replicate row 0
    for (int t = sKept + tid; t < TOPK; t += NT) {
        const int oi = b * TOPK + t;
        out[oi] = sFirst[0];
        out[BS * TOPK + oi] = sFirst[1];
        out[2 * BS * TOPK + oi * 4 + 0] = sFirst[2];
        out[2 * BS * TOPK + oi * 4 + 1] = sFirst[3];
        out[2 * BS * TOPK + oi * 4 + 2] = sFirst[4];
        out[2 * BS * TOPK + oi * 4 + 3] = sFirst[5];
    }
}

extern "C" void kernel_launch(void* const* d_in, const int* in_sizes, int n_in,
                              void* d_out, int out_size, void* d_ws, size_t ws_size,
                              hipStream_t stream) {
    const float* logits = (const float*)d_in[0];   // (8, 900, 91) fp32
    const float* pboxes = (const float*)d_in[1];   // (8, 900, 4) fp32
    const float* ts     = (const float*)d_in[2];   // (8, 2) fp32
    if (ws_size >= WS_REQ) {
        hipMemsetAsync(d_ws, 0, 64, stream);       // zero the 8 pool cursors
        hipLaunchKernelGGL(k1_pool, dim3(NSL, BS), dim3(K1T), 0, stream,
                           logits, d_ws);
        hipLaunchKernelGGL(k2_select_nms, dim3(BS), dim3(NT), 0, stream,
                           logits, pboxes, ts, (float*)d_out, d_ws, 0);
    } else {
        // no workspace: exact in-kernel fallback path (slow, correct)
        hipLaunchKernelGGL(k2_select_nms, dim3(BS), dim3(NT), 0, stream,
                           logits, pboxes, ts, (float*)d_out, d_ws, 1);
    }
}